// Round 15
// baseline (723.572 us; speedup 1.0000x reference)
//
#include <hip/hip_runtime.h>

typedef unsigned int uint;
typedef unsigned short ushort_t;
typedef short bf16x8 __attribute__((ext_vector_type(8)));
typedef float f32x4 __attribute__((ext_vector_type(4)));

constexpr int D_IN   = 768;
constexpr int D_SAE  = 16384;   // 2^14
constexpr int BATCH  = 4096;
constexpr int TOTAL_K = 64 * 4096;              // 262144
constexpr size_t NPRE = (size_t)BATCH * D_SAE;  // 67,108,864
constexpr float WIN_DELTA = 1e-3f;              // exact-window half-width (>=2x worst-case reorder err)
constexpr int   WCAP      = 65536;

// ---------------- workspace layout (bytes) ----------------
// ctrl[1]=bA ctrl[2]=C_A ctrl[3]=thr16_coarse ctrl[5]=nCand ctrl[6]=tau ctrl[7]=nt
// ctrl[8]=bB ctrl[9]=C_B ctrl[10]=tiecnt ctrl[11]=bA_coarse ctrl[12]=C_coarse
// ctrl[13]=thr16_fine ctrl[14]=nFine ctrl[15]=nWindow
constexpr size_t CTRL_OFF    = 0;                          // 16 uints
constexpr size_t HISTA_OFF   = 64;                         // 8192 uints
constexpr size_t HISTB_OFF   = HISTA_OFF + 8192 * 4;       // 4096
constexpr size_t HISTC_OFF   = HISTB_OFF + 4096 * 4;       // 4096
constexpr size_t HISTD_OFF   = HISTC_OFF + 4096 * 4;       // 256
constexpr size_t HISTE_OFF   = HISTD_OFF + 256 * 4;        // 8 (pad 16)
constexpr size_t HISTB2_OFF  = HISTE_OFF + 64;             // 4096
constexpr size_t HISTC2_OFF  = HISTB2_OFF + 4096 * 4;      // 4096
constexpr size_t HISTD2_OFF  = HISTC2_OFF + 4096 * 4;      // 256
constexpr size_t ROWCNT_OFF  = HISTD2_OFF + 256 * 4;       // BATCH
constexpr size_t JCNT_OFF    = ROWCNT_OFF + BATCH * 4;     // D_SAE
constexpr size_t TIEBUF_OFF  = JCNT_OFF + (size_t)D_SAE * 4;  // 2048
constexpr size_t ZERO_BYTES  = TIEBUF_OFF + 2048 * 4;      // memset region end
constexpr size_t ROWOFF_OFF  = ZERO_BYTES;                 // BATCH+64
constexpr size_t CURSOR_OFF  = ROWOFF_OFF + (BATCH + 64) * 4;
constexpr size_t JCURSOR_OFF = CURSOR_OFF + BATCH * 4;     // D_SAE
constexpr size_t JSTART_OFF  = JCURSOR_OFF + (size_t)D_SAE * 4;  // D_SAE+16
constexpr size_t TIEKEEP_OFF = JSTART_OFF + (size_t)(D_SAE + 16) * 4;  // 2048
constexpr size_t WBUF_OFF    = TIEKEEP_OFF + 2048 * 4;     // WCAP uints (256 KB)
constexpr int    CAND_CAP    = 1048576;
constexpr size_t CANDJ_OFF   = WBUF_OFF + (size_t)WCAP * 4;       // uint * CAND_CAP
constexpr size_t CAND_OFF    = CANDJ_OFF + (size_t)CAND_CAP * 4;  // uint2 * CAND_CAP
constexpr size_t GROUPED_OFF = CAND_OFF + (size_t)CAND_CAP * 8;   // uint2*(TOTAL_K+2048)

// dead-z-region scratch offsets (bytes from z base; z = 268,435,456 B total)
constexpr size_t WTF_OFF_Z   = 134217728;                  // fp32 W^T, 48 MB
constexpr size_t WTB_OFF_Z   = WTF_OFF_Z + 50331648;       // bf16 W^T, 24 MB
constexpr size_t XF_OFF_Z    = 230686720;                  // fp32 x - b_dec, 12.6 MB
constexpr size_t WDECB_OFF_Z = 243269632;                  // bf16 W_dec, 24 MB

__device__ __forceinline__ ushort_t f2bf(float f) {        // RNE fp32->bf16 (finite inputs)
  uint u = __float_as_uint(f);
  return (ushort_t)((u + 0x7FFFu + ((u >> 16) & 1u)) >> 16);
}
__device__ __forceinline__ float bf2f(ushort_t b) {
  return __uint_as_float(((uint)b) << 16);
}
__device__ __forceinline__ void gload_lds16(const void* g, void* l) {
  auto gp = reinterpret_cast<const __attribute__((address_space(1))) unsigned int*>(
      (unsigned long long)g);
  auto lp = reinterpret_cast<__attribute__((address_space(3))) unsigned int*>(
      (unsigned long long)l);
  __builtin_amdgcn_global_load_lds(gp, lp, 16, 0, 0);
}

// ---------------- prep: xc_bf16 = bf16(x - b_dec), xf = fp32(x - b_dec) ----------------
__global__ __launch_bounds__(256) void prep_x(const float* __restrict__ x,
                                              const float* __restrict__ bdec,
                                              ushort_t* __restrict__ xc,
                                              float* __restrict__ xf)
{
  int i = blockIdx.x * 256 + threadIdx.x;     // one float4 per thread
  int k4 = i % (D_IN / 4), r = i / (D_IN / 4);
  float4 v  = *(const float4*)(x + (size_t)r * D_IN + k4 * 4);
  float4 bd = *(const float4*)(bdec + k4 * 4);
  float4 d;
  d.x = v.x - bd.x; d.y = v.y - bd.y; d.z = v.z - bd.z; d.w = v.w - bd.w;
  *(float4*)(xf + (size_t)r * D_IN + k4 * 4) = d;
  ushort4 s;
  s.x = f2bf(d.x); s.y = f2bf(d.y); s.z = f2bf(d.z); s.w = f2bf(d.w);
  *(ushort4*)(xc + (size_t)r * D_IN + k4 * 4) = s;
}

// ---------------- transpose W_enc -> WT_f32 [D_SAE][D_IN] + WT_bf16 ----------------
__global__ __launch_bounds__(256) void transpose_w(const float* __restrict__ W,
                                                   float* __restrict__ wtf,
                                                   ushort_t* __restrict__ wtb)
{
  __shared__ float t[64][65];
  int j0 = blockIdx.x * 64;    // D_SAE block
  int k0 = blockIdx.y * 64;    // D_IN block
  int tx = threadIdx.x & 15, ty = threadIdx.x >> 4;
#pragma unroll
  for (int rr = 0; rr < 4; ++rr) {
    float4 v = *(const float4*)(W + (size_t)(k0 + ty + 16 * rr) * D_SAE + j0 + tx * 4);
    t[tx * 4 + 0][ty + 16 * rr] = v.x;
    t[tx * 4 + 1][ty + 16 * rr] = v.y;
    t[tx * 4 + 2][ty + 16 * rr] = v.z;
    t[tx * 4 + 3][ty + 16 * rr] = v.w;
  }
  __syncthreads();
#pragma unroll
  for (int rr = 0; rr < 4; ++rr) {
    int j = j0 + ty + 16 * rr;
    float4 v;
    v.x = t[ty + 16 * rr][tx * 4 + 0];
    v.y = t[ty + 16 * rr][tx * 4 + 1];
    v.z = t[ty + 16 * rr][tx * 4 + 2];
    v.w = t[ty + 16 * rr][tx * 4 + 3];
    *(float4*)(wtf + (size_t)j * D_IN + k0 + tx * 4) = v;
    ushort4 s;
    s.x = f2bf(v.x); s.y = f2bf(v.y); s.z = f2bf(v.z); s.w = f2bf(v.w);
    *(ushort4*)(wtb + (size_t)j * D_IN + k0 + tx * 4) = s;
  }
}

// ---------------- convert W_dec -> bf16 (row-major [D_SAE][D_IN]) ----------------
__global__ __launch_bounds__(256) void conv_wdec(const float* __restrict__ Wdec,
                                                 ushort_t* __restrict__ wdecb)
{
  size_t i = (size_t)blockIdx.x * 256 + threadIdx.x;   // one float4 per thread
  float4 v = *(const float4*)(Wdec + i * 4);
  ushort4 s;
  s.x = f2bf(v.x); s.y = f2bf(v.y); s.z = f2bf(v.z); s.w = f2bf(v.w);
  *(ushort4*)(wdecb + i * 4) = s;
}

// ---------------- bf16 MFMA GEMM: pre_b = bf16(relu(xc @ WT^T + b_enc)) ----------------
__global__ __launch_bounds__(256, 3) void mfma_gemm(
    const ushort_t* __restrict__ xc, const ushort_t* __restrict__ wtb,
    const float* __restrict__ benc,
    ushort_t* __restrict__ pre_b, uint* __restrict__ histA)
{
  __shared__ char smem[32768];                 // As 16384 | Bs 16384 ; reused as hist[8192]
  ushort_t* As = (ushort_t*)smem;              // [128][64] linear, swizzled granules
  ushort_t* Bs = (ushort_t*)(smem + 16384);
  const int tid = threadIdx.x;
  const int m0 = blockIdx.y * 128;
  const int n0 = blockIdx.x * 128;
  const int lane = tid & 63;
  const int wave = tid >> 6;
  const int wr = wave >> 1, wc = wave & 1;
  const int l15 = lane & 15, l4 = lane >> 4;
  const uint srow = (uint)tid >> 3, sg = (uint)tid & 7;

  f32x4 acc[4][4] = {};

  for (int k0 = 0; k0 < D_IN; k0 += 64) {
#pragma unroll
    for (int is = 0; is < 4; ++is) {
      uint row = srow + is * 32;
      uint gsw = sg ^ (row & 7u);
      gload_lds16(xc + (size_t)(m0 + row) * D_IN + k0 + gsw * 8,
                  As + ((size_t)is * 256 + tid) * 8);
      gload_lds16(wtb + (size_t)(n0 + row) * D_IN + k0 + gsw * 8,
                  Bs + ((size_t)is * 256 + tid) * 8);
    }
    __syncthreads();
#pragma unroll
    for (int ks = 0; ks < 2; ++ks) {
      bf16x8 a[4], b[4];
#pragma unroll
      for (int m = 0; m < 4; ++m) {
        int row = wr * 64 + m * 16 + l15;
        int phys = (ks * 4 + l4) ^ (row & 7);
        a[m] = *(const bf16x8*)(As + row * 64 + phys * 8);
      }
#pragma unroll
      for (int n = 0; n < 4; ++n) {
        int row = wc * 64 + n * 16 + l15;
        int phys = (ks * 4 + l4) ^ (row & 7);
        b[n] = *(const bf16x8*)(Bs + row * 64 + phys * 8);
      }
#pragma unroll
      for (int m = 0; m < 4; ++m)
#pragma unroll
        for (int n = 0; n < 4; ++n)
          acc[m][n] = __builtin_amdgcn_mfma_f32_16x16x32_bf16(a[m], b[n], acc[m][n], 0, 0, 0);
    }
    __syncthreads();
  }

  uint* h = (uint*)smem;
  for (int i = tid; i < 8192; i += 256) h[i] = 0;
  __syncthreads();
#pragma unroll
  for (int m = 0; m < 4; ++m) {
#pragma unroll
    for (int n = 0; n < 4; ++n) {
      int col = n0 + wc * 64 + n * 16 + l15;
      float be = benc[col];
#pragma unroll
      for (int r = 0; r < 4; ++r) {
        int row = m0 + wr * 64 + m * 16 + l4 * 4 + r;
        float v = fmaxf(acc[m][n][r] + be, 0.f);
        ushort_t b16 = f2bf(v);
        pre_b[(size_t)row * D_SAE + col] = b16;
        if (b16) atomicAdd(&h[b16 >> 3], 1u);
      }
    }
  }
  __syncthreads();
  for (int i = tid; i < 8192; i += 256) {
    uint c = h[i];
    if (c) atomicAdd(&histA[i], c);
  }
}

// ---------------- coarse approx crossing bin + conservative collect threshold ----------------
__global__ __launch_bounds__(256) void select_thr(const uint* __restrict__ hist, uint* ctrl)
{
  __shared__ uint ssum[256];
  int t = threadIdx.x;
  int hi = 8192 - 32 * t;
  uint sum = 0;
  for (int b = hi - 32; b < hi; ++b) sum += hist[b];
  ssum[t] = sum;
  __syncthreads();
  if (t == 0) {
    uint C = 0;
    int tc = 255;
    for (int i = 0; i < 256; ++i) {
      if (C + ssum[i] >= TOTAL_K) { tc = i; break; }
      C += ssum[i];
    }
    int top = 8192 - 32 * tc - 1;
    uint bin = (uint)(top - 31);
    for (int b = top; b >= top - 31; --b) {
      uint c = hist[b];
      if (C + c >= TOTAL_K) { bin = (uint)b; break; }
      C += c;
    }
    ctrl[11] = bin;
    ctrl[12] = C;
    float binlo = bf2f((ushort_t)(bin << 3));
    float tcf = binlo - 0.03125f;
    uint thr16;
    if (tcf <= 0.f) thr16 = 1u;
    else thr16 = (__float_as_uint(tcf) + 0xFFFFu) >> 16;
    if (thr16 == 0) thr16 = 1u;
    ctrl[3] = thr16;
  }
}

// ---------------- collect candidates: (bits16, idx) for approx >= thr_coarse ----------------
__global__ __launch_bounds__(256) void collect_cands(const ushort_t* __restrict__ pre_b,
                                                     uint* __restrict__ ctrl, uint2* __restrict__ cand)
{
  __shared__ uint2 ents[2048];
  __shared__ uint scnt, sbase;
  if (threadIdx.x == 0) scnt = 0;
  __syncthreads();
  uint thr = ctrl[3];
  size_t n8 = NPRE / 8;
  size_t stride = (size_t)gridDim.x * 256;
  for (size_t i = (size_t)blockIdx.x * 256 + threadIdx.x; i < n8; i += stride) {
    uint4 v = ((const uint4*)pre_b)[i];
    uint base = (uint)(i * 8);
    uint vals[8] = {v.x & 0xFFFFu, v.x >> 16, v.y & 0xFFFFu, v.y >> 16,
                    v.z & 0xFFFFu, v.z >> 16, v.w & 0xFFFFu, v.w >> 16};
#pragma unroll
    for (int c = 0; c < 8; ++c) {
      if (vals[c] >= thr) {
        uint p = atomicAdd(&scnt, 1u);
        if (p < 2048) ents[p] = make_uint2(vals[c], base + c);
        else { uint q = atomicAdd(&ctrl[5], 1u); if (q < CAND_CAP) cand[q] = make_uint2(vals[c], base + c); }
      }
    }
  }
  __syncthreads();
  uint m = min(scnt, 2048u);
  if (threadIdx.x == 0) sbase = atomicAdd(&ctrl[5], m);
  __syncthreads();
  for (uint i = threadIdx.x; i < m; i += 256) {
    uint p = sbase + i;
    if (p < CAND_CAP) cand[p] = ents[i];
  }
}

// ---------------- fine approx hist over the candidate LIST ----------------
__global__ __launch_bounds__(256) void fine_list(const uint* __restrict__ ctrl,
                                                 const uint2* __restrict__ cand,
                                                 uint* __restrict__ histE)
{
  __shared__ uint h[8];
  if (threadIdx.x < 8) h[threadIdx.x] = 0;
  __syncthreads();
  uint bA = ctrl[11];
  uint nC = min(ctrl[5], (uint)CAND_CAP);
  uint stride = gridDim.x * 256;
  for (uint i = blockIdx.x * 256 + threadIdx.x; i < nC; i += stride) {
    uint b = cand[i].x;
    if ((b >> 3) == bA) atomicAdd(&h[b & 7u], 1u);
  }
  __syncthreads();
  if (threadIdx.x < 8) {
    uint c = h[threadIdx.x];
    if (c) atomicAdd(&histE[threadIdx.x], c);
  }
}

// ---------------- exact-bf16 tau_approx -> fine recompute threshold (ctrl[13]) ----------------
__global__ void select_fine(const uint* __restrict__ histE, uint* __restrict__ ctrl)
{
  if (threadIdx.x == 0) {
    uint C = ctrl[12];
    uint bA = ctrl[11];
    int sb = 0;
    for (int b = 7; b >= 0; --b) {
      uint c = histE[b];
      if (C + c >= TOTAL_K) { sb = b; break; }
      C += c;
      if (b == 0) sb = 0;
    }
    ushort_t vstar = (ushort_t)((bA << 3) | (uint)sb);
    float tcf = bf2f(vstar) - 0.03125f;
    uint thr16;
    if (tcf <= 0.f) thr16 = 1u;
    else thr16 = (__float_as_uint(tcf) + 0xFFFFu) >> 16;
    if (thr16 == 0) thr16 = 1u;
    ctrl[13] = thr16;
  }
}

// ---------------- per-column histogram of fine candidates ----------------
__global__ __launch_bounds__(256) void hist_j(const uint* __restrict__ ctrl,
                                              const uint2* __restrict__ cand,
                                              uint* __restrict__ jcnt)
{
  __shared__ uint h[D_SAE];
  for (int i = threadIdx.x; i < D_SAE; i += 256) h[i] = 0;
  __syncthreads();
  uint nC = min(ctrl[5], (uint)CAND_CAP);
  uint thrF = ctrl[13];
  uint stride = gridDim.x * 256;
  for (uint i = blockIdx.x * 256 + threadIdx.x; i < nC; i += stride) {
    uint2 e = cand[i];
    if (e.x >= thrF) atomicAdd(&h[e.y & (D_SAE - 1)], 1u);
  }
  __syncthreads();
  for (int i = threadIdx.x; i < D_SAE; i += 256) {
    uint c = h[i];
    if (c) atomicAdd(&jcnt[i], c);
  }
}

// ---------------- prefix over column counts -> jcursor + jstart; total -> ctrl[14] ----------------
__global__ __launch_bounds__(256) void prefix_j(const uint* __restrict__ jcnt,
                                                uint* __restrict__ jcursor,
                                                uint* __restrict__ jstart,
                                                uint* __restrict__ ctrl)
{
  __shared__ uint s[256];
  __shared__ uint pref[257];
  int t = threadIdx.x;
  uint sum = 0;
  for (int r = 0; r < 64; ++r) sum += jcnt[t * 64 + r];
  s[t] = sum;
  __syncthreads();
  if (t == 0) {
    uint a = 0;
    for (int i = 0; i < 256; ++i) { pref[i] = a; a += s[i]; }
    pref[256] = a;
    ctrl[14] = a;          // nFine
  }
  __syncthreads();
  uint off = pref[t];
  for (int r = 0; r < 64; ++r) {
    int b = t * 64 + r;
    jcursor[b] = off;
    jstart[b] = off;
    off += jcnt[b];
  }
  if (t == 255) jstart[D_SAE] = pref[256];
}

// ---------------- scatter fine candidates into column-grouped order ----------------
__global__ __launch_bounds__(256) void scatter_j(const uint* __restrict__ ctrl,
                                                 const uint2* __restrict__ cand,
                                                 uint* __restrict__ jcursor,
                                                 uint* __restrict__ candJ)
{
  uint nC = min(ctrl[5], (uint)CAND_CAP);
  uint i = blockIdx.x * 256 + threadIdx.x;
  if (i >= nC) return;
  uint2 e = cand[i];
  if (e.x < ctrl[13]) return;
  uint p = atomicAdd(&jcursor[e.y & (D_SAE - 1)], 1u);
  candJ[p] = e.y;
}

// ---------------- fast recompute: block per column, wave-cooperative k-split dot ----------------
// Coalesced: lanes split k (12 elems each), butterfly-reduce. Deterministic but NOT the
// reference chain — elements within WIN_DELTA of tau get exact-chain fixup (exact_fix).
__global__ __launch_bounds__(256) void recompute_fast(
    const float* __restrict__ xf, const float* __restrict__ benc,
    const float* __restrict__ wtf,
    const uint* __restrict__ jstart, const uint* __restrict__ candJ,
    uint2* __restrict__ cand)
{
  __shared__ float wl[D_IN];
  const int j = blockIdx.x;
  uint beg = jstart[j], end = jstart[j + 1];
  if (beg == end) return;                      // uniform across block
  const int t = threadIdx.x;
  wl[t] = wtf[(size_t)j * D_IN + t];
  wl[t + 256] = wtf[(size_t)j * D_IN + t + 256];
  wl[t + 512] = wtf[(size_t)j * D_IN + t + 512];
  __syncthreads();
  const int wv = t >> 6, lane = t & 63;
  const float be = benc[j];
  const float4* wl4 = (const float4*)wl;
  for (uint i = beg + wv; i < end; i += 4) {
    uint idx = candJ[i];
    uint r = idx >> 14;
    const float4* xr4 = (const float4*)(xf + (size_t)r * D_IN);
    float4 x0 = xr4[lane], x1 = xr4[lane + 64], x2 = xr4[lane + 128];
    float4 w0 = wl4[lane], w1 = wl4[lane + 64], w2 = wl4[lane + 128];
    float p = 0.f;
    p = fmaf(x0.x, w0.x, p); p = fmaf(x0.y, w0.y, p);
    p = fmaf(x0.z, w0.z, p); p = fmaf(x0.w, w0.w, p);
    p = fmaf(x1.x, w1.x, p); p = fmaf(x1.y, w1.y, p);
    p = fmaf(x1.z, w1.z, p); p = fmaf(x1.w, w1.w, p);
    p = fmaf(x2.x, w2.x, p); p = fmaf(x2.y, w2.y, p);
    p = fmaf(x2.z, w2.z, p); p = fmaf(x2.w, w2.w, p);
#pragma unroll
    for (int off = 32; off >= 1; off >>= 1)
      p += __shfl_xor(p, off, 64);
    if (lane == 0) {
      float v = fmaxf(p + be, 0.f);
      cand[i] = make_uint2(__float_as_uint(v), idx);
    }
  }
}

// ---------------- collect boundary-window candidates: |v - tau_fast| <= WIN_DELTA ----------------
__global__ __launch_bounds__(256) void window_collect(uint* __restrict__ ctrl,
                                                      const uint2* __restrict__ cand,
                                                      uint* __restrict__ wbuf)
{
  uint nC = min(ctrl[14], (uint)CAND_CAP);
  float tau = __uint_as_float(ctrl[6]);
  uint stride = gridDim.x * 256;
  for (uint i = blockIdx.x * 256 + threadIdx.x; i < nC; i += stride) {
    float v = __uint_as_float(cand[i].x);
    if (fabsf(v - tau) <= WIN_DELTA) {
      uint p = atomicAdd(&ctrl[15], 1u);
      if (p < (uint)WCAP) wbuf[p] = i;
    }
  }
}

// ---------------- exact-chain fixup for window candidates ----------------
// Chain = fmaf(xf[k], w[k], a), k = 0..767 ascending, + benc, relu — bitwise-identical
// to the round-1..12 reference chain.
__global__ __launch_bounds__(256) void exact_fix(
    const float* __restrict__ xf, const float* __restrict__ benc,
    const float* __restrict__ wtf,
    const uint* __restrict__ ctrl, const uint* __restrict__ wbuf,
    uint2* __restrict__ cand)
{
  uint m = min(ctrl[15], (uint)WCAP);
  uint tid = blockIdx.x * 256 + threadIdx.x;
  if (tid >= m) return;
  uint i = wbuf[tid];
  uint idx = cand[i].y;
  uint r = idx >> 14, j = idx & (D_SAE - 1);
  const float* xr = xf + (size_t)r * D_IN;
  const float* wr = wtf + (size_t)j * D_IN;
  float a = 0.f;
  for (int k = 0; k < D_IN; k += 4) {
    float4 xv = *(const float4*)(xr + k);
    float4 wv = *(const float4*)(wr + k);
    a = fmaf(xv.x, wv.x, a);
    a = fmaf(xv.y, wv.y, a);
    a = fmaf(xv.z, wv.z, a);
    a = fmaf(xv.w, wv.w, a);
  }
  float v = fmaxf(a + benc[j], 0.f);
  cand[i] = make_uint2(__float_as_uint(v), idx);
}

// ---------------- 12-bit hist of bits over candidates ----------------
__global__ __launch_bounds__(256) void hist_exact(const uint* __restrict__ ctrl,
                                                  const uint2* __restrict__ cand,
                                                  uint* __restrict__ histB)
{
  __shared__ uint h[4096];
  for (int i = threadIdx.x; i < 4096; i += 256) h[i] = 0;
  __syncthreads();
  uint nC = min(ctrl[14], (uint)CAND_CAP);
  uint stride = gridDim.x * 256;
  for (uint i = blockIdx.x * 256 + threadIdx.x; i < nC; i += stride)
    atomicAdd(&h[cand[i].x >> 20], 1u);
  __syncthreads();
  for (int i = threadIdx.x; i < 4096; i += 256) {
    uint c = h[i];
    if (c) atomicAdd(&histB[i], c);
  }
}

// ---------------- stage-0 crossing-bin search (ctrl[1], ctrl[2]) ----------------
__global__ __launch_bounds__(256) void select_bin(const uint* __restrict__ hist, uint* ctrl)
{
  __shared__ uint ssum[256];
  int t = threadIdx.x;
  int hi = 4096 - 16 * t;
  uint sum = 0;
  for (int b = hi - 16; b < hi; ++b) sum += hist[b];
  ssum[t] = sum;
  __syncthreads();
  if (t == 0) {
    uint C = 0;
    int tc = 255;
    for (int i = 0; i < 256; ++i) {
      if (C + ssum[i] >= TOTAL_K) { tc = i; break; }
      C += ssum[i];
    }
    int top = 4096 - 16 * tc - 1;
    uint bin = (uint)(top - 15);
    for (int b = top; b >= top - 15; --b) {
      uint c = hist[b];
      if (C + c >= TOTAL_K) { bin = (uint)b; break; }
      C += c;
    }
    ctrl[1] = bin;
    ctrl[2] = C;
  }
}

// ---------------- mid-12-bit hist over candidates inside bin bA ----------------
__global__ __launch_bounds__(256) void hist_mid(const uint* __restrict__ ctrl,
                                                const uint2* __restrict__ cand,
                                                uint* __restrict__ histC)
{
  __shared__ uint h[4096];
  for (int i = threadIdx.x; i < 4096; i += 256) h[i] = 0;
  __syncthreads();
  uint nC = min(ctrl[14], (uint)CAND_CAP);
  uint bA = ctrl[1];
  uint stride = gridDim.x * 256;
  for (uint i = blockIdx.x * 256 + threadIdx.x; i < nC; i += stride) {
    uint b = cand[i].x;
    if ((b >> 20) == bA) atomicAdd(&h[(b >> 8) & 0xFFFu], 1u);
  }
  __syncthreads();
  for (int i = threadIdx.x; i < 4096; i += 256) {
    uint c = h[i];
    if (c) atomicAdd(&histC[i], c);
  }
}

// ---------------- mid crossing-bin search (base C_A -> ctrl[8], ctrl[9]) ----------------
__global__ __launch_bounds__(256) void select_mid(const uint* __restrict__ hist, uint* ctrl)
{
  __shared__ uint ssum[256];
  int t = threadIdx.x;
  int hi = 4096 - 16 * t;
  uint sum = 0;
  for (int b = hi - 16; b < hi; ++b) sum += hist[b];
  ssum[t] = sum;
  __syncthreads();
  if (t == 0) {
    uint C = ctrl[2];
    int tc = 255;
    for (int i = 0; i < 256; ++i) {
      if (C + ssum[i] >= TOTAL_K) { tc = i; break; }
      C += ssum[i];
    }
    int top = 4096 - 16 * tc - 1;
    uint bin = (uint)(top - 15);
    for (int b = top; b >= top - 15; --b) {
      uint c = hist[b];
      if (C + c >= TOTAL_K) { bin = (uint)b; break; }
      C += c;
    }
    ctrl[8] = bin;
    ctrl[9] = C;
  }
}

// ---------------- low-8-bit hist over top24 == target ----------------
__global__ __launch_bounds__(256) void hist_low(const uint* __restrict__ ctrl,
                                                const uint2* __restrict__ cand,
                                                uint* __restrict__ histD)
{
  __shared__ uint h[256];
  h[threadIdx.x] = 0;
  __syncthreads();
  uint nC = min(ctrl[14], (uint)CAND_CAP);
  uint target = (ctrl[1] << 12) | ctrl[8];
  uint stride = gridDim.x * 256;
  for (uint i = blockIdx.x * 256 + threadIdx.x; i < nC; i += stride) {
    uint b = cand[i].x;
    if ((b >> 8) == target) atomicAdd(&h[b & 0xFFu], 1u);
  }
  __syncthreads();
  uint c = h[threadIdx.x];
  if (c) atomicAdd(&histD[threadIdx.x], c);
}

// ---------------- final tau selection (1 tiny block) ----------------
__global__ void select_low(const uint* __restrict__ histD, uint* __restrict__ ctrl)
{
  if (threadIdx.x == 0) {
    uint need = TOTAL_K - ctrl[9];   // >= 1
    uint c = 0, v = 0, cgt = 0;
    for (int b = 255; b >= 0; --b) {
      uint hb = histD[b];
      if (c + hb >= need) { v = (uint)b; cgt = c; break; }
      c += hb;
    }
    uint target = (ctrl[1] << 12) | ctrl[8];
    ctrl[6] = (target << 8) | v;     // tau
    ctrl[7] = need - cgt;            // nt >= 1
  }
}

// ---------------- collect ==tau ties ----------------
__global__ __launch_bounds__(256) void collect_ties(uint* __restrict__ ctrl,
                                                    const uint2* __restrict__ cand,
                                                    uint* __restrict__ tiebuf)
{
  uint nC = min(ctrl[14], (uint)CAND_CAP);
  uint tau = ctrl[6];
  uint stride = gridDim.x * 256;
  for (uint i = blockIdx.x * 256 + threadIdx.x; i < nC; i += stride) {
    if (cand[i].x == tau) {
      uint p = atomicAdd(&ctrl[10], 1u);
      if (p < 2048) tiebuf[p] = cand[i].y;
    }
  }
}

// ---------------- rank ties, keep nt smallest flat indices ----------------
__global__ __launch_bounds__(256) void tie_rank(const uint* __restrict__ ctrl,
                                                const uint* __restrict__ tiebuf,
                                                uint* __restrict__ tiekeep)
{
  __shared__ uint s_tie[2048];
  uint m = min(ctrl[10], 2048u);
  uint nt = ctrl[7];
  for (uint i = threadIdx.x; i < m; i += 256) s_tie[i] = tiebuf[i];
  __syncthreads();
  for (uint i = threadIdx.x; i < m; i += 256) {
    uint my = s_tie[i];
    uint rank = 0;
    for (uint j = 0; j < m; ++j) rank += (s_tie[j] < my) ? 1u : 0u;
    if (rank < nt) tiekeep[rank] = my;
  }
}

// ---------------- count kept entries per row ----------------
__global__ __launch_bounds__(256) void count_rows(const uint* __restrict__ ctrl, const uint2* __restrict__ cand,
                                                  const uint* __restrict__ tiekeep,
                                                  uint* __restrict__ rowcnt)
{
  uint nC = min(ctrl[14], (uint)CAND_CAP);
  uint i = blockIdx.x * 256 + threadIdx.x;
  if (i >= nC) return;
  uint tau = ctrl[6], nt = ctrl[7];
  uint2 e = cand[i];
  bool keep = e.x > tau;
  if (!keep && e.x == tau) {
    for (uint j = 0; j < nt; ++j)
      if (tiekeep[j] == e.y) { keep = true; break; }
  }
  if (keep) atomicAdd(&rowcnt[e.y >> 14], 1u);
}

// ---------------- prefix sum over row counts ----------------
__global__ __launch_bounds__(256) void prefix_rows(const uint* __restrict__ rowcnt,
                                                   uint* __restrict__ rowoff, uint* __restrict__ cursor)
{
  __shared__ uint s[256];
  __shared__ uint pref[257];
  int t = threadIdx.x;
  uint loc[16], sum = 0;
#pragma unroll
  for (int r = 0; r < 16; ++r) { loc[r] = rowcnt[t * 16 + r]; sum += loc[r]; }
  s[t] = sum;
  __syncthreads();
  if (t == 0) {
    uint a = 0;
    for (int i = 0; i < 256; ++i) { pref[i] = a; a += s[i]; }
    pref[256] = a;
  }
  __syncthreads();
  uint off = pref[t];
#pragma unroll
  for (int r = 0; r < 16; ++r) {
    rowoff[t * 16 + r] = off;
    cursor[t * 16 + r] = off;
    off += loc[r];
  }
  if (t == 255) rowoff[BATCH] = off;
}

// ---------------- group kept entries by row ----------------
__global__ __launch_bounds__(256) void group_pass(const uint* __restrict__ ctrl, const uint2* __restrict__ cand,
                                                  const uint* __restrict__ tiekeep,
                                                  uint* __restrict__ cursor, uint2* __restrict__ grouped)
{
  uint nC = min(ctrl[14], (uint)CAND_CAP);
  uint i = blockIdx.x * 256 + threadIdx.x;
  if (i >= nC) return;
  uint tau = ctrl[6], nt = ctrl[7];
  uint2 e = cand[i];
  bool keep = e.x > tau;
  if (!keep && e.x == tau) {
    for (uint j = 0; j < nt; ++j)
      if (tiekeep[j] == e.y) { keep = true; break; }
  }
  if (keep) {
    uint p = atomicAdd(&cursor[e.y >> 14], 1u);
    grouped[p] = make_uint2(e.y, e.x);   // (flat idx, bits)
  }
}

// ---------------- sparse decode (bf16 W_dec, ushort4-vectorized, 192 threads) ----------------
__global__ __launch_bounds__(192) void decode_kernel(const uint* __restrict__ rowoff, const uint2* __restrict__ grouped,
                                                     const ushort_t* __restrict__ wdecb, const float* __restrict__ bdec,
                                                     float* __restrict__ xhat)
{
  int r = blockIdx.x;
  int t = threadIdx.x;          // 0..191, owns cols 4t..4t+3
  uint beg = rowoff[r], end = rowoff[r + 1];
  float4 a = *(const float4*)(bdec + t * 4);
  __shared__ uint2 ch[128];
  for (uint c0 = beg; c0 < end; c0 += 128) {
    uint m = min(128u, end - c0);
    if (t < (int)m) ch[t] = grouped[c0 + t];
    __syncthreads();
    for (uint e = 0; e < m; ++e) {
      uint2 en = ch[e];
      float v = __uint_as_float(en.y);
      uint j = en.x & (D_SAE - 1);
      ushort4 w4 = *(const ushort4*)(wdecb + (size_t)j * D_IN + t * 4);
      a.x = fmaf(v, bf2f(w4.x), a.x);
      a.y = fmaf(v, bf2f(w4.y), a.y);
      a.z = fmaf(v, bf2f(w4.z), a.z);
      a.w = fmaf(v, bf2f(w4.w), a.w);
    }
    __syncthreads();
  }
  *(float4*)(xhat + (size_t)r * D_IN + t * 4) = a;
}

// ---------------- scatter kept values into zeroed z ----------------
__global__ __launch_bounds__(256) void scatter_kept(const uint* __restrict__ ctrl, const uint2* __restrict__ cand,
                                                    const uint* __restrict__ tiekeep,
                                                    float* __restrict__ z)
{
  uint nC = min(ctrl[14], (uint)CAND_CAP);
  uint i = blockIdx.x * 256 + threadIdx.x;
  if (i >= nC) return;
  uint tau = ctrl[6], nt = ctrl[7];
  uint2 e = cand[i];
  bool keep = e.x > tau;
  if (!keep && e.x == tau) {
    for (uint j = 0; j < nt; ++j)
      if (tiekeep[j] == e.y) { keep = true; break; }
  }
  if (keep) z[e.y] = __uint_as_float(e.x);
}

extern "C" void kernel_launch(void* const* d_in, const int* in_sizes, int n_in,
                              void* d_out, int out_size, void* d_ws, size_t ws_size,
                              hipStream_t stream)
{
  const float* x    = (const float*)d_in[0];
  const float* Wenc = (const float*)d_in[1];
  const float* benc = (const float*)d_in[2];
  const float* Wdec = (const float*)d_in[3];
  const float* bdec = (const float*)d_in[4];

  char* outb = (char*)d_out;
  float*    xhat   = (float*)outb;
  ushort_t* xc     = (ushort_t*)outb;
  char*     zb     = outb + (size_t)BATCH * D_IN * 4;
  float*    z      = (float*)zb;
  ushort_t* pre_b  = (ushort_t*)zb;
  float*    wtf    = (float*)(zb + WTF_OFF_Z);
  ushort_t* wtb    = (ushort_t*)(zb + WTB_OFF_Z);
  float*    xf     = (float*)(zb + XF_OFF_Z);
  ushort_t* wdecb  = (ushort_t*)(zb + WDECB_OFF_Z);

  char* ws = (char*)d_ws;
  uint*  ctrl    = (uint*)(ws + CTRL_OFF);
  uint*  histA   = (uint*)(ws + HISTA_OFF);
  uint*  histB   = (uint*)(ws + HISTB_OFF);
  uint*  histC   = (uint*)(ws + HISTC_OFF);
  uint*  histD   = (uint*)(ws + HISTD_OFF);
  uint*  histE   = (uint*)(ws + HISTE_OFF);
  uint*  histB2  = (uint*)(ws + HISTB2_OFF);
  uint*  histC2  = (uint*)(ws + HISTC2_OFF);
  uint*  histD2  = (uint*)(ws + HISTD2_OFF);
  uint*  rowcnt  = (uint*)(ws + ROWCNT_OFF);
  uint*  jcnt    = (uint*)(ws + JCNT_OFF);
  uint*  tiebuf  = (uint*)(ws + TIEBUF_OFF);
  uint*  rowoff  = (uint*)(ws + ROWOFF_OFF);
  uint*  cursor  = (uint*)(ws + CURSOR_OFF);
  uint*  jcursor = (uint*)(ws + JCURSOR_OFF);
  uint*  jstart  = (uint*)(ws + JSTART_OFF);
  uint*  tiekeep = (uint*)(ws + TIEKEEP_OFF);
  uint*  wbuf    = (uint*)(ws + WBUF_OFF);
  uint*  candJ   = (uint*)(ws + CANDJ_OFF);
  uint2* cand    = (uint2*)(ws + CAND_OFF);
  uint2* grouped = (uint2*)(ws + GROUPED_OFF);

  (void)hipMemsetAsync(d_ws, 0, ZERO_BYTES, stream);

  prep_x<<<BATCH * D_IN / 4 / 256, 256, 0, stream>>>(x, bdec, xc, xf);
  transpose_w<<<dim3(D_SAE / 64, D_IN / 64), 256, 0, stream>>>(Wenc, wtf, wtb);
  conv_wdec<<<(D_SAE * D_IN / 4) / 256, 256, 0, stream>>>(Wdec, wdecb);
  mfma_gemm<<<dim3(D_SAE / 128, BATCH / 128), 256, 0, stream>>>(xc, wtb, benc, pre_b, histA);

  select_thr<<<1, 256, 0, stream>>>(histA, ctrl);
  collect_cands<<<1024, 256, 0, stream>>>(pre_b, ctrl, cand);
  fine_list<<<64, 256, 0, stream>>>(ctrl, cand, histE);
  select_fine<<<1, 64, 0, stream>>>(histE, ctrl);

  hist_j<<<64, 256, 0, stream>>>(ctrl, cand, jcnt);
  prefix_j<<<1, 256, 0, stream>>>(jcnt, jcursor, jstart, ctrl);
  scatter_j<<<CAND_CAP / 256, 256, 0, stream>>>(ctrl, cand, jcursor, candJ);
  recompute_fast<<<D_SAE, 256, 0, stream>>>(xf, benc, wtf, jstart, candJ, cand);

  // pass 1: selection on fast values -> tau_fast in ctrl[6]
  hist_exact<<<128, 256, 0, stream>>>(ctrl, cand, histB);
  select_bin<<<1, 256, 0, stream>>>(histB, ctrl);
  hist_mid<<<128, 256, 0, stream>>>(ctrl, cand, histC);
  select_mid<<<1, 256, 0, stream>>>(histC, ctrl);
  hist_low<<<128, 256, 0, stream>>>(ctrl, cand, histD);
  select_low<<<1, 64, 0, stream>>>(histD, ctrl);

  // exact-chain fixup of the boundary window, then re-select
  window_collect<<<128, 256, 0, stream>>>(ctrl, cand, wbuf);
  exact_fix<<<WCAP / 256, 256, 0, stream>>>(xf, benc, wtf, ctrl, wbuf, cand);
  hist_exact<<<128, 256, 0, stream>>>(ctrl, cand, histB2);
  select_bin<<<1, 256, 0, stream>>>(histB2, ctrl);
  hist_mid<<<128, 256, 0, stream>>>(ctrl, cand, histC2);
  select_mid<<<1, 256, 0, stream>>>(histC2, ctrl);
  hist_low<<<128, 256, 0, stream>>>(ctrl, cand, histD2);
  select_low<<<1, 64, 0, stream>>>(histD2, ctrl);

  collect_ties<<<128, 256, 0, stream>>>(ctrl, cand, tiebuf);
  tie_rank<<<1, 256, 0, stream>>>(ctrl, tiebuf, tiekeep);

  // decode BEFORE the z memset so wdec_b (in the dead z region) stays intact
  count_rows<<<CAND_CAP / 256, 256, 0, stream>>>(ctrl, cand, tiekeep, rowcnt);
  prefix_rows<<<1, 256, 0, stream>>>(rowcnt, rowoff, cursor);
  group_pass<<<CAND_CAP / 256, 256, 0, stream>>>(ctrl, cand, tiekeep, cursor, grouped);
  decode_kernel<<<BATCH, 192, 0, stream>>>(rowoff, grouped, wdecb, bdec, xhat);

  (void)hipMemsetAsync(z, 0, NPRE * 4, stream);
  scatter_kept<<<CAND_CAP / 256, 256, 0, stream>>>(ctrl, cand, tiekeep, z);
}

// Round 16
// 680.228 us; speedup vs baseline: 1.0637x; 1.0637x over previous
//
#include <hip/hip_runtime.h>

typedef unsigned int uint;
typedef unsigned short ushort_t;
typedef short bf16x8 __attribute__((ext_vector_type(8)));
typedef float f32x4 __attribute__((ext_vector_type(4)));

constexpr int D_IN   = 768;
constexpr int D_SAE  = 16384;   // 2^14
constexpr int BATCH  = 4096;
constexpr int TOTAL_K = 64 * 4096;              // 262144
constexpr size_t NPRE = (size_t)BATCH * D_SAE;  // 67,108,864

// ---------------- workspace layout (bytes) ----------------
// ctrl[1]=bA ctrl[2]=C_A ctrl[3]=thr16_coarse ctrl[5]=nCand ctrl[6]=tau ctrl[7]=nt
// ctrl[8]=bB ctrl[9]=C_B ctrl[10]=tiecnt ctrl[11]=bA_coarse ctrl[12]=C_coarse
// ctrl[13]=thr16_fine ctrl[14]=nFine
constexpr size_t CTRL_OFF    = 0;                          // 16 uints
constexpr size_t HISTA_OFF   = 64;                         // 8192 uints (13-bit approx hist)
constexpr size_t HISTB_OFF   = HISTA_OFF + 8192 * 4;       // 4096 uints (top-12 exact)
constexpr size_t HISTC_OFF   = HISTB_OFF + 4096 * 4;       // 4096 uints (mid-12 exact)
constexpr size_t HISTD_OFF   = HISTC_OFF + 4096 * 4;       // 256 uints (low-8 exact)
constexpr size_t HISTE_OFF   = HISTD_OFF + 256 * 4;        // 8 uints (fine approx sub-bins)
constexpr size_t ROWCNT_OFF  = HISTE_OFF + 64;             // BATCH uints
constexpr size_t JCNT_OFF    = ROWCNT_OFF + BATCH * 4;     // D_SAE uints (64 KB)
constexpr size_t TIEBUF_OFF  = JCNT_OFF + (size_t)D_SAE * 4;  // 2048 uints
constexpr size_t ZERO_BYTES  = TIEBUF_OFF + 2048 * 4;      // memset region end
constexpr size_t ROWOFF_OFF  = ZERO_BYTES;                 // BATCH+1 uints (pad)
constexpr size_t CURSOR_OFF  = ROWOFF_OFF + (BATCH + 64) * 4;
constexpr size_t JCURSOR_OFF = CURSOR_OFF + BATCH * 4;     // D_SAE uints
constexpr size_t JSTART_OFF  = JCURSOR_OFF + (size_t)D_SAE * 4;  // D_SAE+16 uints
constexpr size_t TIEKEEP_OFF = JSTART_OFF + (size_t)(D_SAE + 16) * 4;  // 2048 uints
constexpr int    CAND_CAP    = 1048576;
constexpr size_t CANDJ_OFF   = TIEKEEP_OFF + 2048 * 4;     // uint  * CAND_CAP (4 MB)
constexpr size_t CAND_OFF    = CANDJ_OFF + (size_t)CAND_CAP * 4;  // uint2 * CAND_CAP (8 MB)
constexpr size_t GROUPED_OFF = CAND_OFF + (size_t)CAND_CAP * 8;   // uint2*(TOTAL_K+2048)

// dead-z-region scratch offsets (bytes from z base; z = 268,435,456 B total)
constexpr size_t WTF_OFF_Z   = 134217728;                  // fp32 W^T, 48 MB (after pre_b)
constexpr size_t WTB_OFF_Z   = WTF_OFF_Z + 50331648;       // bf16 W^T, 24 MB
constexpr size_t XF_OFF_Z    = 230686720;                  // fp32 x - b_dec, 12.6 MB
constexpr size_t WDECB_OFF_Z = 243269632;                  // bf16 W_dec, 24 MB (read by decode, pre-memset)

__device__ __forceinline__ ushort_t f2bf(float f) {        // RNE fp32->bf16 (finite inputs)
  uint u = __float_as_uint(f);
  return (ushort_t)((u + 0x7FFFu + ((u >> 16) & 1u)) >> 16);
}
__device__ __forceinline__ float bf2f(ushort_t b) {
  return __uint_as_float(((uint)b) << 16);
}
__device__ __forceinline__ void gload_lds16(const void* g, void* l) {
  auto gp = reinterpret_cast<const __attribute__((address_space(1))) unsigned int*>(
      (unsigned long long)g);
  auto lp = reinterpret_cast<__attribute__((address_space(3))) unsigned int*>(
      (unsigned long long)l);
  __builtin_amdgcn_global_load_lds(gp, lp, 16, 0, 0);
}

// ---------------- zero z with wide contiguous stores (runtime fill kernel is ~4x
// write-amplified: 1.12 GB HBM writes / 160 us for a 268 MB buffer) ----------------
__global__ __launch_bounds__(256) void zero_z(uint4* __restrict__ z)
{
  const uint4 zero4 = make_uint4(0, 0, 0, 0);
  size_t n16 = NPRE / 4;                       // 16.7M uint4
  size_t stride = (size_t)gridDim.x * 256;
  for (size_t i = (size_t)blockIdx.x * 256 + threadIdx.x; i < n16; i += stride)
    z[i] = zero4;
}

// ---------------- prep: xc_bf16 = bf16(x - b_dec), xf = fp32(x - b_dec) ----------------
__global__ __launch_bounds__(256) void prep_x(const float* __restrict__ x,
                                              const float* __restrict__ bdec,
                                              ushort_t* __restrict__ xc,
                                              float* __restrict__ xf)
{
  int i = blockIdx.x * 256 + threadIdx.x;     // one float4 per thread
  int k4 = i % (D_IN / 4), r = i / (D_IN / 4);
  float4 v  = *(const float4*)(x + (size_t)r * D_IN + k4 * 4);
  float4 bd = *(const float4*)(bdec + k4 * 4);
  float4 d;
  d.x = v.x - bd.x; d.y = v.y - bd.y; d.z = v.z - bd.z; d.w = v.w - bd.w;
  *(float4*)(xf + (size_t)r * D_IN + k4 * 4) = d;
  ushort4 s;
  s.x = f2bf(d.x); s.y = f2bf(d.y); s.z = f2bf(d.z); s.w = f2bf(d.w);
  *(ushort4*)(xc + (size_t)r * D_IN + k4 * 4) = s;
}

// ---------------- transpose W_enc -> WT_f32 [D_SAE][D_IN] + WT_bf16 ----------------
__global__ __launch_bounds__(256) void transpose_w(const float* __restrict__ W,
                                                   float* __restrict__ wtf,
                                                   ushort_t* __restrict__ wtb)
{
  __shared__ float t[64][65];
  int j0 = blockIdx.x * 64;    // D_SAE block
  int k0 = blockIdx.y * 64;    // D_IN block
  int tx = threadIdx.x & 15, ty = threadIdx.x >> 4;
#pragma unroll
  for (int rr = 0; rr < 4; ++rr) {
    float4 v = *(const float4*)(W + (size_t)(k0 + ty + 16 * rr) * D_SAE + j0 + tx * 4);
    t[tx * 4 + 0][ty + 16 * rr] = v.x;
    t[tx * 4 + 1][ty + 16 * rr] = v.y;
    t[tx * 4 + 2][ty + 16 * rr] = v.z;
    t[tx * 4 + 3][ty + 16 * rr] = v.w;
  }
  __syncthreads();
#pragma unroll
  for (int rr = 0; rr < 4; ++rr) {
    int j = j0 + ty + 16 * rr;
    float4 v;
    v.x = t[ty + 16 * rr][tx * 4 + 0];
    v.y = t[ty + 16 * rr][tx * 4 + 1];
    v.z = t[ty + 16 * rr][tx * 4 + 2];
    v.w = t[ty + 16 * rr][tx * 4 + 3];
    *(float4*)(wtf + (size_t)j * D_IN + k0 + tx * 4) = v;
    ushort4 s;
    s.x = f2bf(v.x); s.y = f2bf(v.y); s.z = f2bf(v.z); s.w = f2bf(v.w);
    *(ushort4*)(wtb + (size_t)j * D_IN + k0 + tx * 4) = s;
  }
}

// ---------------- convert W_dec -> bf16 (row-major [D_SAE][D_IN]) ----------------
__global__ __launch_bounds__(256) void conv_wdec(const float* __restrict__ Wdec,
                                                 ushort_t* __restrict__ wdecb)
{
  size_t i = (size_t)blockIdx.x * 256 + threadIdx.x;   // one float4 per thread
  float4 v = *(const float4*)(Wdec + i * 4);
  ushort4 s;
  s.x = f2bf(v.x); s.y = f2bf(v.y); s.z = f2bf(v.z); s.w = f2bf(v.w);
  *(ushort4*)(wdecb + i * 4) = s;
}

// ---------------- bf16 MFMA GEMM: pre_b = bf16(relu(xc @ WT^T + b_enc)) ----------------
__global__ __launch_bounds__(256, 3) void mfma_gemm(
    const ushort_t* __restrict__ xc, const ushort_t* __restrict__ wtb,
    const float* __restrict__ benc,
    ushort_t* __restrict__ pre_b, uint* __restrict__ histA)
{
  __shared__ char smem[32768];                 // As 16384 | Bs 16384 ; reused as hist[8192]
  ushort_t* As = (ushort_t*)smem;              // [128][64] linear, swizzled granules
  ushort_t* Bs = (ushort_t*)(smem + 16384);
  const int tid = threadIdx.x;
  const int m0 = blockIdx.y * 128;
  const int n0 = blockIdx.x * 128;
  const int lane = tid & 63;
  const int wave = tid >> 6;
  const int wr = wave >> 1, wc = wave & 1;
  const int l15 = lane & 15, l4 = lane >> 4;
  const uint srow = (uint)tid >> 3, sg = (uint)tid & 7;

  f32x4 acc[4][4] = {};

  for (int k0 = 0; k0 < D_IN; k0 += 64) {
#pragma unroll
    for (int is = 0; is < 4; ++is) {
      uint row = srow + is * 32;
      uint gsw = sg ^ (row & 7u);
      gload_lds16(xc + (size_t)(m0 + row) * D_IN + k0 + gsw * 8,
                  As + ((size_t)is * 256 + tid) * 8);
      gload_lds16(wtb + (size_t)(n0 + row) * D_IN + k0 + gsw * 8,
                  Bs + ((size_t)is * 256 + tid) * 8);
    }
    __syncthreads();
#pragma unroll
    for (int ks = 0; ks < 2; ++ks) {
      bf16x8 a[4], b[4];
#pragma unroll
      for (int m = 0; m < 4; ++m) {
        int row = wr * 64 + m * 16 + l15;
        int phys = (ks * 4 + l4) ^ (row & 7);
        a[m] = *(const bf16x8*)(As + row * 64 + phys * 8);
      }
#pragma unroll
      for (int n = 0; n < 4; ++n) {
        int row = wc * 64 + n * 16 + l15;
        int phys = (ks * 4 + l4) ^ (row & 7);
        b[n] = *(const bf16x8*)(Bs + row * 64 + phys * 8);
      }
#pragma unroll
      for (int m = 0; m < 4; ++m)
#pragma unroll
        for (int n = 0; n < 4; ++n)
          acc[m][n] = __builtin_amdgcn_mfma_f32_16x16x32_bf16(a[m], b[n], acc[m][n], 0, 0, 0);
    }
    __syncthreads();
  }

  uint* h = (uint*)smem;
  for (int i = tid; i < 8192; i += 256) h[i] = 0;
  __syncthreads();
#pragma unroll
  for (int m = 0; m < 4; ++m) {
#pragma unroll
    for (int n = 0; n < 4; ++n) {
      int col = n0 + wc * 64 + n * 16 + l15;
      float be = benc[col];
#pragma unroll
      for (int r = 0; r < 4; ++r) {
        int row = m0 + wr * 64 + m * 16 + l4 * 4 + r;
        float v = fmaxf(acc[m][n][r] + be, 0.f);
        ushort_t b16 = f2bf(v);
        pre_b[(size_t)row * D_SAE + col] = b16;
        if (b16) atomicAdd(&h[b16 >> 3], 1u);
      }
    }
  }
  __syncthreads();
  for (int i = tid; i < 8192; i += 256) {
    uint c = h[i];
    if (c) atomicAdd(&histA[i], c);
  }
}

// ---------------- coarse approx crossing bin + conservative collect threshold ----------------
__global__ __launch_bounds__(256) void select_thr(const uint* __restrict__ hist, uint* ctrl)
{
  __shared__ uint ssum[256];
  int t = threadIdx.x;
  int hi = 8192 - 32 * t;
  uint sum = 0;
  for (int b = hi - 32; b < hi; ++b) sum += hist[b];
  ssum[t] = sum;
  __syncthreads();
  if (t == 0) {
    uint C = 0;
    int tc = 255;
    for (int i = 0; i < 256; ++i) {
      if (C + ssum[i] >= TOTAL_K) { tc = i; break; }
      C += ssum[i];
    }
    int top = 8192 - 32 * tc - 1;
    uint bin = (uint)(top - 31);
    for (int b = top; b >= top - 31; --b) {
      uint c = hist[b];
      if (C + c >= TOTAL_K) { bin = (uint)b; break; }
      C += c;
    }
    ctrl[11] = bin;
    ctrl[12] = C;
    float binlo = bf2f((ushort_t)(bin << 3));
    float tcf = binlo - 0.03125f;
    uint thr16;
    if (tcf <= 0.f) thr16 = 1u;
    else thr16 = (__float_as_uint(tcf) + 0xFFFFu) >> 16;
    if (thr16 == 0) thr16 = 1u;
    ctrl[3] = thr16;
  }
}

// ---------------- collect candidates: (bits16, idx) for approx >= thr_coarse ----------------
__global__ __launch_bounds__(256) void collect_cands(const ushort_t* __restrict__ pre_b,
                                                     uint* __restrict__ ctrl, uint2* __restrict__ cand)
{
  __shared__ uint2 ents[2048];
  __shared__ uint scnt, sbase;
  if (threadIdx.x == 0) scnt = 0;
  __syncthreads();
  uint thr = ctrl[3];
  size_t n8 = NPRE / 8;
  size_t stride = (size_t)gridDim.x * 256;
  for (size_t i = (size_t)blockIdx.x * 256 + threadIdx.x; i < n8; i += stride) {
    uint4 v = ((const uint4*)pre_b)[i];
    uint base = (uint)(i * 8);
    uint vals[8] = {v.x & 0xFFFFu, v.x >> 16, v.y & 0xFFFFu, v.y >> 16,
                    v.z & 0xFFFFu, v.z >> 16, v.w & 0xFFFFu, v.w >> 16};
#pragma unroll
    for (int c = 0; c < 8; ++c) {
      if (vals[c] >= thr) {
        uint p = atomicAdd(&scnt, 1u);
        if (p < 2048) ents[p] = make_uint2(vals[c], base + c);
        else { uint q = atomicAdd(&ctrl[5], 1u); if (q < CAND_CAP) cand[q] = make_uint2(vals[c], base + c); }
      }
    }
  }
  __syncthreads();
  uint m = min(scnt, 2048u);
  if (threadIdx.x == 0) sbase = atomicAdd(&ctrl[5], m);
  __syncthreads();
  for (uint i = threadIdx.x; i < m; i += 256) {
    uint p = sbase + i;
    if (p < CAND_CAP) cand[p] = ents[i];
  }
}

// ---------------- fine approx hist over the candidate LIST ----------------
__global__ __launch_bounds__(256) void fine_list(const uint* __restrict__ ctrl,
                                                 const uint2* __restrict__ cand,
                                                 uint* __restrict__ histE)
{
  __shared__ uint h[8];
  if (threadIdx.x < 8) h[threadIdx.x] = 0;
  __syncthreads();
  uint bA = ctrl[11];
  uint nC = min(ctrl[5], (uint)CAND_CAP);
  uint stride = gridDim.x * 256;
  for (uint i = blockIdx.x * 256 + threadIdx.x; i < nC; i += stride) {
    uint b = cand[i].x;
    if ((b >> 3) == bA) atomicAdd(&h[b & 7u], 1u);
  }
  __syncthreads();
  if (threadIdx.x < 8) {
    uint c = h[threadIdx.x];
    if (c) atomicAdd(&histE[threadIdx.x], c);
  }
}

// ---------------- exact-bf16 tau_approx -> fine recompute threshold (ctrl[13]) ----------------
__global__ void select_fine(const uint* __restrict__ histE, uint* __restrict__ ctrl)
{
  if (threadIdx.x == 0) {
    uint C = ctrl[12];
    uint bA = ctrl[11];
    int sb = 0;
    for (int b = 7; b >= 0; --b) {
      uint c = histE[b];
      if (C + c >= TOTAL_K) { sb = b; break; }
      C += c;
      if (b == 0) sb = 0;
    }
    ushort_t vstar = (ushort_t)((bA << 3) | (uint)sb);
    float tcf = bf2f(vstar) - 0.03125f;
    uint thr16;
    if (tcf <= 0.f) thr16 = 1u;
    else thr16 = (__float_as_uint(tcf) + 0xFFFFu) >> 16;
    if (thr16 == 0) thr16 = 1u;
    ctrl[13] = thr16;
  }
}

// ---------------- per-column histogram of fine candidates ----------------
__global__ __launch_bounds__(256) void hist_j(const uint* __restrict__ ctrl,
                                              const uint2* __restrict__ cand,
                                              uint* __restrict__ jcnt)
{
  __shared__ uint h[D_SAE];
  for (int i = threadIdx.x; i < D_SAE; i += 256) h[i] = 0;
  __syncthreads();
  uint nC = min(ctrl[5], (uint)CAND_CAP);
  uint thrF = ctrl[13];
  uint stride = gridDim.x * 256;
  for (uint i = blockIdx.x * 256 + threadIdx.x; i < nC; i += stride) {
    uint2 e = cand[i];
    if (e.x >= thrF) atomicAdd(&h[e.y & (D_SAE - 1)], 1u);
  }
  __syncthreads();
  for (int i = threadIdx.x; i < D_SAE; i += 256) {
    uint c = h[i];
    if (c) atomicAdd(&jcnt[i], c);
  }
}

// ---------------- prefix over column counts -> jcursor + jstart; total -> ctrl[14] ----------------
__global__ __launch_bounds__(256) void prefix_j(const uint* __restrict__ jcnt,
                                                uint* __restrict__ jcursor,
                                                uint* __restrict__ jstart,
                                                uint* __restrict__ ctrl)
{
  __shared__ uint s[256];
  __shared__ uint pref[257];
  int t = threadIdx.x;
  uint sum = 0;
  for (int r = 0; r < 64; ++r) sum += jcnt[t * 64 + r];
  s[t] = sum;
  __syncthreads();
  if (t == 0) {
    uint a = 0;
    for (int i = 0; i < 256; ++i) { pref[i] = a; a += s[i]; }
    pref[256] = a;
    ctrl[14] = a;          // nFine
  }
  __syncthreads();
  uint off = pref[t];
  for (int r = 0; r < 64; ++r) {
    int b = t * 64 + r;
    jcursor[b] = off;
    jstart[b] = off;
    off += jcnt[b];
  }
  if (t == 255) jstart[D_SAE] = pref[256];
}

// ---------------- scatter fine candidates into column-grouped order ----------------
__global__ __launch_bounds__(256) void scatter_j(const uint* __restrict__ ctrl,
                                                 const uint2* __restrict__ cand,
                                                 uint* __restrict__ jcursor,
                                                 uint* __restrict__ candJ)
{
  uint nC = min(ctrl[5], (uint)CAND_CAP);
  uint i = blockIdx.x * 256 + threadIdx.x;
  if (i >= nC) return;
  uint2 e = cand[i];
  if (e.x < ctrl[13]) return;
  uint p = atomicAdd(&jcursor[e.y & (D_SAE - 1)], 1u);
  candJ[p] = e.y;
}

// ---------------- exact recompute: one WAVE per column, W row staged in LDS ----------------
// Per-candidate chain = fmaf(xf[k], w[k], a), k = 0..767 ascending, + benc, relu —
// bitwise-identical to rounds 1..14.
__global__ __launch_bounds__(256) void recompute(
    const float* __restrict__ xf, const float* __restrict__ benc,
    const float* __restrict__ wtf,
    const uint* __restrict__ jstart, const uint* __restrict__ candJ,
    uint2* __restrict__ cand)
{
  __shared__ float wl[4][D_IN];
  const int wv = threadIdx.x >> 6, lane = threadIdx.x & 63;
  const int j = blockIdx.x * 4 + wv;
  uint beg = jstart[j], end = jstart[j + 1];
  const float4* wr4 = (const float4*)(wtf + (size_t)j * D_IN);
  float4* wl4 = (float4*)wl[wv];
#pragma unroll
  for (int k = 0; k < 3; ++k) wl4[lane + 64 * k] = wr4[lane + 64 * k];
  __syncthreads();
  if (beg == end) return;
  float be = benc[j];
  const float* w = wl[wv];
  for (uint i = beg + lane; i < end; i += 64) {
    uint idx = candJ[i];
    uint r = idx >> 14;
    const float* xr = xf + (size_t)r * D_IN;
    float a = 0.f;
#pragma unroll 8
    for (int k = 0; k < D_IN; k += 4) {
      float4 xv = *(const float4*)(xr + k);
      a = fmaf(xv.x, w[k + 0], a);
      a = fmaf(xv.y, w[k + 1], a);
      a = fmaf(xv.z, w[k + 2], a);
      a = fmaf(xv.w, w[k + 3], a);
    }
    float v = fmaxf(a + be, 0.f);
    cand[i] = make_uint2(__float_as_uint(v), idx);
  }
}

// ---------------- 12-bit hist of exact bits over recomputed candidates ----------------
__global__ __launch_bounds__(256) void hist_exact(const uint* __restrict__ ctrl,
                                                  const uint2* __restrict__ cand,
                                                  uint* __restrict__ histB)
{
  __shared__ uint h[4096];
  for (int i = threadIdx.x; i < 4096; i += 256) h[i] = 0;
  __syncthreads();
  uint nC = min(ctrl[14], (uint)CAND_CAP);
  uint stride = gridDim.x * 256;
  for (uint i = blockIdx.x * 256 + threadIdx.x; i < nC; i += stride)
    atomicAdd(&h[cand[i].x >> 20], 1u);
  __syncthreads();
  for (int i = threadIdx.x; i < 4096; i += 256) {
    uint c = h[i];
    if (c) atomicAdd(&histB[i], c);
  }
}

// ---------------- exact stage-0 crossing-bin search (ctrl[1], ctrl[2]) ----------------
__global__ __launch_bounds__(256) void select_bin(const uint* __restrict__ hist, uint* ctrl)
{
  __shared__ uint ssum[256];
  int t = threadIdx.x;
  int hi = 4096 - 16 * t;
  uint sum = 0;
  for (int b = hi - 16; b < hi; ++b) sum += hist[b];
  ssum[t] = sum;
  __syncthreads();
  if (t == 0) {
    uint C = 0;
    int tc = 255;
    for (int i = 0; i < 256; ++i) {
      if (C + ssum[i] >= TOTAL_K) { tc = i; break; }
      C += ssum[i];
    }
    int top = 4096 - 16 * tc - 1;
    uint bin = (uint)(top - 15);
    for (int b = top; b >= top - 15; --b) {
      uint c = hist[b];
      if (C + c >= TOTAL_K) { bin = (uint)b; break; }
      C += c;
    }
    ctrl[1] = bin;
    ctrl[2] = C;
  }
}

// ---------------- mid-12-bit hist over candidates inside bin bA ----------------
__global__ __launch_bounds__(256) void hist_mid(const uint* __restrict__ ctrl,
                                                const uint2* __restrict__ cand,
                                                uint* __restrict__ histC)
{
  __shared__ uint h[4096];
  for (int i = threadIdx.x; i < 4096; i += 256) h[i] = 0;
  __syncthreads();
  uint nC = min(ctrl[14], (uint)CAND_CAP);
  uint bA = ctrl[1];
  uint stride = gridDim.x * 256;
  for (uint i = blockIdx.x * 256 + threadIdx.x; i < nC; i += stride) {
    uint b = cand[i].x;
    if ((b >> 20) == bA) atomicAdd(&h[(b >> 8) & 0xFFFu], 1u);
  }
  __syncthreads();
  for (int i = threadIdx.x; i < 4096; i += 256) {
    uint c = h[i];
    if (c) atomicAdd(&histC[i], c);
  }
}

// ---------------- mid crossing-bin search (base C_A -> ctrl[8], ctrl[9]) ----------------
__global__ __launch_bounds__(256) void select_mid(const uint* __restrict__ hist, uint* ctrl)
{
  __shared__ uint ssum[256];
  int t = threadIdx.x;
  int hi = 4096 - 16 * t;
  uint sum = 0;
  for (int b = hi - 16; b < hi; ++b) sum += hist[b];
  ssum[t] = sum;
  __syncthreads();
  if (t == 0) {
    uint C = ctrl[2];
    int tc = 255;
    for (int i = 0; i < 256; ++i) {
      if (C + ssum[i] >= TOTAL_K) { tc = i; break; }
      C += ssum[i];
    }
    int top = 4096 - 16 * tc - 1;
    uint bin = (uint)(top - 15);
    for (int b = top; b >= top - 15; --b) {
      uint c = hist[b];
      if (C + c >= TOTAL_K) { bin = (uint)b; break; }
      C += c;
    }
    ctrl[8] = bin;
    ctrl[9] = C;
  }
}

// ---------------- low-8-bit hist over top24 == target ----------------
__global__ __launch_bounds__(256) void hist_low(const uint* __restrict__ ctrl,
                                                const uint2* __restrict__ cand,
                                                uint* __restrict__ histD)
{
  __shared__ uint h[256];
  h[threadIdx.x] = 0;
  __syncthreads();
  uint nC = min(ctrl[14], (uint)CAND_CAP);
  uint target = (ctrl[1] << 12) | ctrl[8];
  uint stride = gridDim.x * 256;
  for (uint i = blockIdx.x * 256 + threadIdx.x; i < nC; i += stride) {
    uint b = cand[i].x;
    if ((b >> 8) == target) atomicAdd(&h[b & 0xFFu], 1u);
  }
  __syncthreads();
  uint c = h[threadIdx.x];
  if (c) atomicAdd(&histD[threadIdx.x], c);
}

// ---------------- final tau selection (1 tiny block) ----------------
__global__ void select_low(const uint* __restrict__ histD, uint* __restrict__ ctrl)
{
  if (threadIdx.x == 0) {
    uint need = TOTAL_K - ctrl[9];   // >= 1
    uint c = 0, v = 0, cgt = 0;
    for (int b = 255; b >= 0; --b) {
      uint hb = histD[b];
      if (c + hb >= need) { v = (uint)b; cgt = c; break; }
      c += hb;
    }
    uint target = (ctrl[1] << 12) | ctrl[8];
    ctrl[6] = (target << 8) | v;     // tau
    ctrl[7] = need - cgt;            // nt >= 1
  }
}

// ---------------- collect ==tau ties ----------------
__global__ __launch_bounds__(256) void collect_ties(uint* __restrict__ ctrl,
                                                    const uint2* __restrict__ cand,
                                                    uint* __restrict__ tiebuf)
{
  uint nC = min(ctrl[14], (uint)CAND_CAP);
  uint tau = ctrl[6];
  uint stride = gridDim.x * 256;
  for (uint i = blockIdx.x * 256 + threadIdx.x; i < nC; i += stride) {
    if (cand[i].x == tau) {
      uint p = atomicAdd(&ctrl[10], 1u);
      if (p < 2048) tiebuf[p] = cand[i].y;
    }
  }
}

// ---------------- rank ties, keep nt smallest flat indices ----------------
__global__ __launch_bounds__(256) void tie_rank(const uint* __restrict__ ctrl,
                                                const uint* __restrict__ tiebuf,
                                                uint* __restrict__ tiekeep)
{
  __shared__ uint s_tie[2048];
  uint m = min(ctrl[10], 2048u);
  uint nt = ctrl[7];
  for (uint i = threadIdx.x; i < m; i += 256) s_tie[i] = tiebuf[i];
  __syncthreads();
  for (uint i = threadIdx.x; i < m; i += 256) {
    uint my = s_tie[i];
    uint rank = 0;
    for (uint j = 0; j < m; ++j) rank += (s_tie[j] < my) ? 1u : 0u;
    if (rank < nt) tiekeep[rank] = my;
  }
}

// ---------------- count kept entries per row ----------------
__global__ __launch_bounds__(256) void count_rows(const uint* __restrict__ ctrl, const uint2* __restrict__ cand,
                                                  const uint* __restrict__ tiekeep,
                                                  uint* __restrict__ rowcnt)
{
  uint nC = min(ctrl[14], (uint)CAND_CAP);
  uint i = blockIdx.x * 256 + threadIdx.x;
  if (i >= nC) return;
  uint tau = ctrl[6], nt = ctrl[7];
  uint2 e = cand[i];
  bool keep = e.x > tau;
  if (!keep && e.x == tau) {
    for (uint j = 0; j < nt; ++j)
      if (tiekeep[j] == e.y) { keep = true; break; }
  }
  if (keep) atomicAdd(&rowcnt[e.y >> 14], 1u);
}

// ---------------- prefix sum over row counts ----------------
__global__ __launch_bounds__(256) void prefix_rows(const uint* __restrict__ rowcnt,
                                                   uint* __restrict__ rowoff, uint* __restrict__ cursor)
{
  __shared__ uint s[256];
  __shared__ uint pref[257];
  int t = threadIdx.x;
  uint loc[16], sum = 0;
#pragma unroll
  for (int r = 0; r < 16; ++r) { loc[r] = rowcnt[t * 16 + r]; sum += loc[r]; }
  s[t] = sum;
  __syncthreads();
  if (t == 0) {
    uint a = 0;
    for (int i = 0; i < 256; ++i) { pref[i] = a; a += s[i]; }
    pref[256] = a;
  }
  __syncthreads();
  uint off = pref[t];
#pragma unroll
  for (int r = 0; r < 16; ++r) {
    rowoff[t * 16 + r] = off;
    cursor[t * 16 + r] = off;
    off += loc[r];
  }
  if (t == 255) rowoff[BATCH] = off;
}

// ---------------- group kept entries by row ----------------
__global__ __launch_bounds__(256) void group_pass(const uint* __restrict__ ctrl, const uint2* __restrict__ cand,
                                                  const uint* __restrict__ tiekeep,
                                                  uint* __restrict__ cursor, uint2* __restrict__ grouped)
{
  uint nC = min(ctrl[14], (uint)CAND_CAP);
  uint i = blockIdx.x * 256 + threadIdx.x;
  if (i >= nC) return;
  uint tau = ctrl[6], nt = ctrl[7];
  uint2 e = cand[i];
  bool keep = e.x > tau;
  if (!keep && e.x == tau) {
    for (uint j = 0; j < nt; ++j)
      if (tiekeep[j] == e.y) { keep = true; break; }
  }
  if (keep) {
    uint p = atomicAdd(&cursor[e.y >> 14], 1u);
    grouped[p] = make_uint2(e.y, e.x);   // (flat idx, bits)
  }
}

// ---------------- sparse decode (bf16 W_dec, ushort4-vectorized, 192 threads) ----------------
__global__ __launch_bounds__(192) void decode_kernel(const uint* __restrict__ rowoff, const uint2* __restrict__ grouped,
                                                     const ushort_t* __restrict__ wdecb, const float* __restrict__ bdec,
                                                     float* __restrict__ xhat)
{
  int r = blockIdx.x;
  int t = threadIdx.x;          // 0..191, owns cols 4t..4t+3
  uint beg = rowoff[r], end = rowoff[r + 1];
  float4 a = *(const float4*)(bdec + t * 4);
  __shared__ uint2 ch[128];
  for (uint c0 = beg; c0 < end; c0 += 128) {
    uint m = min(128u, end - c0);
    if (t < (int)m) ch[t] = grouped[c0 + t];
    __syncthreads();
    for (uint e = 0; e < m; ++e) {
      uint2 en = ch[e];
      float v = __uint_as_float(en.y);
      uint j = en.x & (D_SAE - 1);
      ushort4 w4 = *(const ushort4*)(wdecb + (size_t)j * D_IN + t * 4);
      a.x = fmaf(v, bf2f(w4.x), a.x);
      a.y = fmaf(v, bf2f(w4.y), a.y);
      a.z = fmaf(v, bf2f(w4.z), a.z);
      a.w = fmaf(v, bf2f(w4.w), a.w);
    }
    __syncthreads();
  }
  *(float4*)(xhat + (size_t)r * D_IN + t * 4) = a;
}

// ---------------- scatter kept values into zeroed z ----------------
__global__ __launch_bounds__(256) void scatter_kept(const uint* __restrict__ ctrl, const uint2* __restrict__ cand,
                                                    const uint* __restrict__ tiekeep,
                                                    float* __restrict__ z)
{
  uint nC = min(ctrl[14], (uint)CAND_CAP);
  uint i = blockIdx.x * 256 + threadIdx.x;
  if (i >= nC) return;
  uint tau = ctrl[6], nt = ctrl[7];
  uint2 e = cand[i];
  bool keep = e.x > tau;
  if (!keep && e.x == tau) {
    for (uint j = 0; j < nt; ++j)
      if (tiekeep[j] == e.y) { keep = true; break; }
  }
  if (keep) z[e.y] = __uint_as_float(e.x);
}

extern "C" void kernel_launch(void* const* d_in, const int* in_sizes, int n_in,
                              void* d_out, int out_size, void* d_ws, size_t ws_size,
                              hipStream_t stream)
{
  const float* x    = (const float*)d_in[0];
  const float* Wenc = (const float*)d_in[1];
  const float* benc = (const float*)d_in[2];
  const float* Wdec = (const float*)d_in[3];
  const float* bdec = (const float*)d_in[4];

  char* outb = (char*)d_out;
  float*    xhat   = (float*)outb;
  ushort_t* xc     = (ushort_t*)outb;
  char*     zb     = outb + (size_t)BATCH * D_IN * 4;
  float*    z      = (float*)zb;
  ushort_t* pre_b  = (ushort_t*)zb;
  float*    wtf    = (float*)(zb + WTF_OFF_Z);
  ushort_t* wtb    = (ushort_t*)(zb + WTB_OFF_Z);
  float*    xf     = (float*)(zb + XF_OFF_Z);
  ushort_t* wdecb  = (ushort_t*)(zb + WDECB_OFF_Z);

  char* ws = (char*)d_ws;
  uint*  ctrl    = (uint*)(ws + CTRL_OFF);
  uint*  histA   = (uint*)(ws + HISTA_OFF);
  uint*  histB   = (uint*)(ws + HISTB_OFF);
  uint*  histC   = (uint*)(ws + HISTC_OFF);
  uint*  histD   = (uint*)(ws + HISTD_OFF);
  uint*  histE   = (uint*)(ws + HISTE_OFF);
  uint*  rowcnt  = (uint*)(ws + ROWCNT_OFF);
  uint*  jcnt    = (uint*)(ws + JCNT_OFF);
  uint*  tiebuf  = (uint*)(ws + TIEBUF_OFF);
  uint*  rowoff  = (uint*)(ws + ROWOFF_OFF);
  uint*  cursor  = (uint*)(ws + CURSOR_OFF);
  uint*  jcursor = (uint*)(ws + JCURSOR_OFF);
  uint*  jstart  = (uint*)(ws + JSTART_OFF);
  uint*  tiekeep = (uint*)(ws + TIEKEEP_OFF);
  uint*  candJ   = (uint*)(ws + CANDJ_OFF);
  uint2* cand    = (uint2*)(ws + CAND_OFF);
  uint2* grouped = (uint2*)(ws + GROUPED_OFF);

  (void)hipMemsetAsync(d_ws, 0, ZERO_BYTES, stream);

  prep_x<<<BATCH * D_IN / 4 / 256, 256, 0, stream>>>(x, bdec, xc, xf);
  transpose_w<<<dim3(D_SAE / 64, D_IN / 64), 256, 0, stream>>>(Wenc, wtf, wtb);
  conv_wdec<<<(D_SAE * D_IN / 4) / 256, 256, 0, stream>>>(Wdec, wdecb);
  mfma_gemm<<<dim3(D_SAE / 128, BATCH / 128), 256, 0, stream>>>(xc, wtb, benc, pre_b, histA);

  select_thr<<<1, 256, 0, stream>>>(histA, ctrl);
  collect_cands<<<1024, 256, 0, stream>>>(pre_b, ctrl, cand);
  fine_list<<<64, 256, 0, stream>>>(ctrl, cand, histE);
  select_fine<<<1, 64, 0, stream>>>(histE, ctrl);

  hist_j<<<64, 256, 0, stream>>>(ctrl, cand, jcnt);
  prefix_j<<<1, 256, 0, stream>>>(jcnt, jcursor, jstart, ctrl);
  scatter_j<<<CAND_CAP / 256, 256, 0, stream>>>(ctrl, cand, jcursor, candJ);
  recompute<<<D_SAE / 4, 256, 0, stream>>>(xf, benc, wtf, jstart, candJ, cand);
  hist_exact<<<128, 256, 0, stream>>>(ctrl, cand, histB);

  select_bin<<<1, 256, 0, stream>>>(histB, ctrl);
  hist_mid<<<128, 256, 0, stream>>>(ctrl, cand, histC);
  select_mid<<<1, 256, 0, stream>>>(histC, ctrl);
  hist_low<<<128, 256, 0, stream>>>(ctrl, cand, histD);
  select_low<<<1, 64, 0, stream>>>(histD, ctrl);
  collect_ties<<<128, 256, 0, stream>>>(ctrl, cand, tiebuf);
  tie_rank<<<1, 256, 0, stream>>>(ctrl, tiebuf, tiekeep);

  // decode BEFORE the z zeroing so wdec_b (in the dead z region) stays intact
  count_rows<<<CAND_CAP / 256, 256, 0, stream>>>(ctrl, cand, tiekeep, rowcnt);
  prefix_rows<<<1, 256, 0, stream>>>(rowcnt, rowoff, cursor);
  group_pass<<<CAND_CAP / 256, 256, 0, stream>>>(ctrl, cand, tiekeep, cursor, grouped);
  decode_kernel<<<BATCH, 192, 0, stream>>>(rowoff, grouped, wdecb, bdec, xhat);

  zero_z<<<2048, 256, 0, stream>>>((uint4*)z);
  scatter_kept<<<CAND_CAP / 256, 256, 0, stream>>>(ctrl, cand, tiekeep, z);
}

// Round 17
// 628.343 us; speedup vs baseline: 1.1516x; 1.0826x over previous
//
#include <hip/hip_runtime.h>

typedef unsigned int uint;
typedef unsigned short ushort_t;
typedef short bf16x8 __attribute__((ext_vector_type(8)));
typedef float f32x4 __attribute__((ext_vector_type(4)));

constexpr int D_IN   = 768;
constexpr int D_SAE  = 16384;   // 2^14
constexpr int BATCH  = 4096;
constexpr int TOTAL_K = 64 * 4096;              // 262144
constexpr size_t NPRE = (size_t)BATCH * D_SAE;  // 67,108,864

// ---------------- workspace layout (bytes) ----------------
// ctrl[1]=bA ctrl[2]=C_A ctrl[3]=thr16_coarse ctrl[5]=nCand ctrl[6]=tau ctrl[7]=nt
// ctrl[8]=bB ctrl[9]=C_B ctrl[10]=tiecnt ctrl[11]=bA_coarse ctrl[12]=C_coarse
// ctrl[13]=band_lo(f32 bits) ctrl[14]=nBand ctrl[15]=band_hi(f32 bits)
constexpr size_t CTRL_OFF    = 0;                          // 16 uints
constexpr size_t HISTA_OFF   = 64;                         // 8192 uints (13-bit approx hist)
constexpr size_t HISTB_OFF   = HISTA_OFF + 8192 * 4;       // 4096 uints (top-12 exact)
constexpr size_t HISTC_OFF   = HISTB_OFF + 4096 * 4;       // 4096 uints (mid-12 exact)
constexpr size_t HISTD_OFF   = HISTC_OFF + 4096 * 4;       // 256 uints (low-8 exact)
constexpr size_t HISTE_OFF   = HISTD_OFF + 256 * 4;        // 8 uints (fine approx sub-bins)
constexpr size_t ROWCNT_OFF  = HISTE_OFF + 64;             // BATCH uints
constexpr size_t JCNT_OFF    = ROWCNT_OFF + BATCH * 4;     // D_SAE uints (64 KB)
constexpr size_t TIEBUF_OFF  = JCNT_OFF + (size_t)D_SAE * 4;  // 2048 uints
constexpr size_t ZERO_BYTES  = TIEBUF_OFF + 2048 * 4;      // memset region end
constexpr size_t ROWOFF_OFF  = ZERO_BYTES;                 // BATCH+1 uints (pad)
constexpr size_t CURSOR_OFF  = ROWOFF_OFF + (BATCH + 64) * 4;
constexpr size_t JCURSOR_OFF = CURSOR_OFF + BATCH * 4;     // D_SAE uints
constexpr size_t JSTART_OFF  = JCURSOR_OFF + (size_t)D_SAE * 4;  // D_SAE+16 uints
constexpr size_t TIEKEEP_OFF = JSTART_OFF + (size_t)(D_SAE + 16) * 4;  // 2048 uints
constexpr int    CAND_CAP    = 1048576;
constexpr size_t CANDJ_OFF   = TIEKEEP_OFF + 2048 * 4;     // uint  * CAND_CAP (4 MB)
constexpr size_t CAND_OFF    = CANDJ_OFF + (size_t)CAND_CAP * 4;  // uint2 * CAND_CAP (8 MB)
constexpr size_t GROUPED_OFF = CAND_OFF + (size_t)CAND_CAP * 8;   // uint2*(TOTAL_K+2048)

// dead-z-region scratch offsets (bytes from z base; z = 268,435,456 B total)
constexpr size_t WTF_OFF_Z   = 134217728;                  // fp32 W^T, 48 MB (after pre_b)
constexpr size_t WTB_OFF_Z   = WTF_OFF_Z + 50331648;       // bf16 W^T, 24 MB
constexpr size_t XF_OFF_Z    = 230686720;                  // fp32 x - b_dec, 12.6 MB
constexpr size_t WDECB_OFF_Z = 243269632;                  // bf16 W_dec, 24 MB (read by decode, pre-memset)

__device__ __forceinline__ ushort_t f2bf(float f) {        // RNE fp32->bf16 (finite inputs)
  uint u = __float_as_uint(f);
  return (ushort_t)((u + 0x7FFFu + ((u >> 16) & 1u)) >> 16);
}
__device__ __forceinline__ float bf2f(ushort_t b) {
  return __uint_as_float(((uint)b) << 16);
}
__device__ __forceinline__ void gload_lds16(const void* g, void* l) {
  auto gp = reinterpret_cast<const __attribute__((address_space(1))) unsigned int*>(
      (unsigned long long)g);
  auto lp = reinterpret_cast<__attribute__((address_space(3))) unsigned int*>(
      (unsigned long long)l);
  __builtin_amdgcn_global_load_lds(gp, lp, 16, 0, 0);
}

// ---------------- zero z with wide contiguous stores ----------------
__global__ __launch_bounds__(256) void zero_z(uint4* __restrict__ z)
{
  const uint4 zero4 = make_uint4(0, 0, 0, 0);
  size_t n16 = NPRE / 4;
  size_t stride = (size_t)gridDim.x * 256;
  for (size_t i = (size_t)blockIdx.x * 256 + threadIdx.x; i < n16; i += stride)
    z[i] = zero4;
}

// ---------------- prep: xc_bf16 = bf16(x - b_dec), xf = fp32(x - b_dec) ----------------
__global__ __launch_bounds__(256) void prep_x(const float* __restrict__ x,
                                              const float* __restrict__ bdec,
                                              ushort_t* __restrict__ xc,
                                              float* __restrict__ xf)
{
  int i = blockIdx.x * 256 + threadIdx.x;     // one float4 per thread
  int k4 = i % (D_IN / 4), r = i / (D_IN / 4);
  float4 v  = *(const float4*)(x + (size_t)r * D_IN + k4 * 4);
  float4 bd = *(const float4*)(bdec + k4 * 4);
  float4 d;
  d.x = v.x - bd.x; d.y = v.y - bd.y; d.z = v.z - bd.z; d.w = v.w - bd.w;
  *(float4*)(xf + (size_t)r * D_IN + k4 * 4) = d;
  ushort4 s;
  s.x = f2bf(d.x); s.y = f2bf(d.y); s.z = f2bf(d.z); s.w = f2bf(d.w);
  *(ushort4*)(xc + (size_t)r * D_IN + k4 * 4) = s;
}

// ---------------- transpose W_enc -> WT_f32 [D_SAE][D_IN] + WT_bf16 ----------------
__global__ __launch_bounds__(256) void transpose_w(const float* __restrict__ W,
                                                   float* __restrict__ wtf,
                                                   ushort_t* __restrict__ wtb)
{
  __shared__ float t[64][65];
  int j0 = blockIdx.x * 64;    // D_SAE block
  int k0 = blockIdx.y * 64;    // D_IN block
  int tx = threadIdx.x & 15, ty = threadIdx.x >> 4;
#pragma unroll
  for (int rr = 0; rr < 4; ++rr) {
    float4 v = *(const float4*)(W + (size_t)(k0 + ty + 16 * rr) * D_SAE + j0 + tx * 4);
    t[tx * 4 + 0][ty + 16 * rr] = v.x;
    t[tx * 4 + 1][ty + 16 * rr] = v.y;
    t[tx * 4 + 2][ty + 16 * rr] = v.z;
    t[tx * 4 + 3][ty + 16 * rr] = v.w;
  }
  __syncthreads();
#pragma unroll
  for (int rr = 0; rr < 4; ++rr) {
    int j = j0 + ty + 16 * rr;
    float4 v;
    v.x = t[ty + 16 * rr][tx * 4 + 0];
    v.y = t[ty + 16 * rr][tx * 4 + 1];
    v.z = t[ty + 16 * rr][tx * 4 + 2];
    v.w = t[ty + 16 * rr][tx * 4 + 3];
    *(float4*)(wtf + (size_t)j * D_IN + k0 + tx * 4) = v;
    ushort4 s;
    s.x = f2bf(v.x); s.y = f2bf(v.y); s.z = f2bf(v.z); s.w = f2bf(v.w);
    *(ushort4*)(wtb + (size_t)j * D_IN + k0 + tx * 4) = s;
  }
}

// ---------------- convert W_dec -> bf16 (row-major [D_SAE][D_IN]) ----------------
__global__ __launch_bounds__(256) void conv_wdec(const float* __restrict__ Wdec,
                                                 ushort_t* __restrict__ wdecb)
{
  size_t i = (size_t)blockIdx.x * 256 + threadIdx.x;   // one float4 per thread
  float4 v = *(const float4*)(Wdec + i * 4);
  ushort4 s;
  s.x = f2bf(v.x); s.y = f2bf(v.y); s.z = f2bf(v.z); s.w = f2bf(v.w);
  *(ushort4*)(wdecb + i * 4) = s;
}

// ---------------- bf16 MFMA GEMM: pre_b = bf16(relu(xc @ WT^T + b_enc)) ----------------
__global__ __launch_bounds__(256, 3) void mfma_gemm(
    const ushort_t* __restrict__ xc, const ushort_t* __restrict__ wtb,
    const float* __restrict__ benc,
    ushort_t* __restrict__ pre_b, uint* __restrict__ histA)
{
  __shared__ char smem[32768];                 // As 16384 | Bs 16384 ; reused as hist[8192]
  ushort_t* As = (ushort_t*)smem;              // [128][64] linear, swizzled granules
  ushort_t* Bs = (ushort_t*)(smem + 16384);
  const int tid = threadIdx.x;
  const int m0 = blockIdx.y * 128;
  const int n0 = blockIdx.x * 128;
  const int lane = tid & 63;
  const int wave = tid >> 6;
  const int wr = wave >> 1, wc = wave & 1;
  const int l15 = lane & 15, l4 = lane >> 4;
  const uint srow = (uint)tid >> 3, sg = (uint)tid & 7;

  f32x4 acc[4][4] = {};

  for (int k0 = 0; k0 < D_IN; k0 += 64) {
#pragma unroll
    for (int is = 0; is < 4; ++is) {
      uint row = srow + is * 32;
      uint gsw = sg ^ (row & 7u);
      gload_lds16(xc + (size_t)(m0 + row) * D_IN + k0 + gsw * 8,
                  As + ((size_t)is * 256 + tid) * 8);
      gload_lds16(wtb + (size_t)(n0 + row) * D_IN + k0 + gsw * 8,
                  Bs + ((size_t)is * 256 + tid) * 8);
    }
    __syncthreads();
#pragma unroll
    for (int ks = 0; ks < 2; ++ks) {
      bf16x8 a[4], b[4];
#pragma unroll
      for (int m = 0; m < 4; ++m) {
        int row = wr * 64 + m * 16 + l15;
        int phys = (ks * 4 + l4) ^ (row & 7);
        a[m] = *(const bf16x8*)(As + row * 64 + phys * 8);
      }
#pragma unroll
      for (int n = 0; n < 4; ++n) {
        int row = wc * 64 + n * 16 + l15;
        int phys = (ks * 4 + l4) ^ (row & 7);
        b[n] = *(const bf16x8*)(Bs + row * 64 + phys * 8);
      }
#pragma unroll
      for (int m = 0; m < 4; ++m)
#pragma unroll
        for (int n = 0; n < 4; ++n)
          acc[m][n] = __builtin_amdgcn_mfma_f32_16x16x32_bf16(a[m], b[n], acc[m][n], 0, 0, 0);
    }
    __syncthreads();
  }

  uint* h = (uint*)smem;
  for (int i = tid; i < 8192; i += 256) h[i] = 0;
  __syncthreads();
#pragma unroll
  for (int m = 0; m < 4; ++m) {
#pragma unroll
    for (int n = 0; n < 4; ++n) {
      int col = n0 + wc * 64 + n * 16 + l15;
      float be = benc[col];
#pragma unroll
      for (int r = 0; r < 4; ++r) {
        int row = m0 + wr * 64 + m * 16 + l4 * 4 + r;
        float v = fmaxf(acc[m][n][r] + be, 0.f);
        ushort_t b16 = f2bf(v);
        pre_b[(size_t)row * D_SAE + col] = b16;
        if (b16) atomicAdd(&h[b16 >> 3], 1u);
      }
    }
  }
  __syncthreads();
  for (int i = tid; i < 8192; i += 256) {
    uint c = h[i];
    if (c) atomicAdd(&histA[i], c);
  }
}

// ---------------- coarse approx crossing bin + conservative collect threshold ----------------
__global__ __launch_bounds__(256) void select_thr(const uint* __restrict__ hist, uint* ctrl)
{
  __shared__ uint ssum[256];
  int t = threadIdx.x;
  int hi = 8192 - 32 * t;
  uint sum = 0;
  for (int b = hi - 32; b < hi; ++b) sum += hist[b];
  ssum[t] = sum;
  __syncthreads();
  if (t == 0) {
    uint C = 0;
    int tc = 255;
    for (int i = 0; i < 256; ++i) {
      if (C + ssum[i] >= TOTAL_K) { tc = i; break; }
      C += ssum[i];
    }
    int top = 8192 - 32 * tc - 1;
    uint bin = (uint)(top - 31);
    for (int b = top; b >= top - 31; --b) {
      uint c = hist[b];
      if (C + c >= TOTAL_K) { bin = (uint)b; break; }
      C += c;
    }
    ctrl[11] = bin;
    ctrl[12] = C;
    float binlo = bf2f((ushort_t)(bin << 3));
    float tcf = binlo - 0.03125f;
    uint thr16;
    if (tcf <= 0.f) thr16 = 1u;
    else thr16 = (__float_as_uint(tcf) + 0xFFFFu) >> 16;
    if (thr16 == 0) thr16 = 1u;
    ctrl[3] = thr16;
  }
}

// ---------------- collect candidates: (bits16, idx) for approx >= thr_coarse ----------------
__global__ __launch_bounds__(256) void collect_cands(const ushort_t* __restrict__ pre_b,
                                                     uint* __restrict__ ctrl, uint2* __restrict__ cand)
{
  __shared__ uint2 ents[2048];
  __shared__ uint scnt, sbase;
  if (threadIdx.x == 0) scnt = 0;
  __syncthreads();
  uint thr = ctrl[3];
  size_t n8 = NPRE / 8;
  size_t stride = (size_t)gridDim.x * 256;
  for (size_t i = (size_t)blockIdx.x * 256 + threadIdx.x; i < n8; i += stride) {
    uint4 v = ((const uint4*)pre_b)[i];
    uint base = (uint)(i * 8);
    uint vals[8] = {v.x & 0xFFFFu, v.x >> 16, v.y & 0xFFFFu, v.y >> 16,
                    v.z & 0xFFFFu, v.z >> 16, v.w & 0xFFFFu, v.w >> 16};
#pragma unroll
    for (int c = 0; c < 8; ++c) {
      if (vals[c] >= thr) {
        uint p = atomicAdd(&scnt, 1u);
        if (p < 2048) ents[p] = make_uint2(vals[c], base + c);
        else { uint q = atomicAdd(&ctrl[5], 1u); if (q < CAND_CAP) cand[q] = make_uint2(vals[c], base + c); }
      }
    }
  }
  __syncthreads();
  uint m = min(scnt, 2048u);
  if (threadIdx.x == 0) sbase = atomicAdd(&ctrl[5], m);
  __syncthreads();
  for (uint i = threadIdx.x; i < m; i += 256) {
    uint p = sbase + i;
    if (p < CAND_CAP) cand[p] = ents[i];
  }
}

// ---------------- fine approx hist over the candidate LIST (bits16) ----------------
__global__ __launch_bounds__(256) void fine_list(const uint* __restrict__ ctrl,
                                                 const uint2* __restrict__ cand,
                                                 uint* __restrict__ histE)
{
  __shared__ uint h[8];
  if (threadIdx.x < 8) h[threadIdx.x] = 0;
  __syncthreads();
  uint bA = ctrl[11];
  uint nC = min(ctrl[5], (uint)CAND_CAP);
  uint stride = gridDim.x * 256;
  for (uint i = blockIdx.x * 256 + threadIdx.x; i < nC; i += stride) {
    uint b = cand[i].x;
    if ((b >> 3) == bA) atomicAdd(&h[b & 7u], 1u);
  }
  __syncthreads();
  if (threadIdx.x < 8) {
    uint c = h[threadIdx.x];
    if (c) atomicAdd(&histE[threadIdx.x], c);
  }
}

// ---------------- exact-bf16 tau_approx -> boundary band [lo, hi] (ctrl[13], ctrl[15]) ----------------
__global__ void select_fine(const uint* __restrict__ histE, uint* __restrict__ ctrl)
{
  if (threadIdx.x == 0) {
    uint C = ctrl[12];
    uint bA = ctrl[11];
    int sb = 0;
    for (int b = 7; b >= 0; --b) {
      uint c = histE[b];
      if (C + c >= TOTAL_K) { sb = b; break; }
      C += c;
      if (b == 0) sb = 0;
    }
    float tf = bf2f((ushort_t)((bA << 3) | (uint)sb));   // tau_approx (bf16-exact)
    // band half-width 0.03125 >= 3x worst-case |exact - bf16approx| (~0.01)
    ctrl[13] = __float_as_uint(tf - 0.03125f);
    ctrl[15] = __float_as_uint(tf + 0.03125f);
  }
}

// ---------------- convert bits16 -> f32 bits in-place; per-column hist of BAND members ----------------
__global__ __launch_bounds__(256) void convert_band(const uint* __restrict__ ctrl,
                                                    uint2* __restrict__ cand,
                                                    uint* __restrict__ jcnt)
{
  __shared__ uint h[D_SAE];
  for (int i = threadIdx.x; i < D_SAE; i += 256) h[i] = 0;
  __syncthreads();
  uint nC = min(ctrl[5], (uint)CAND_CAP);
  float lo = __uint_as_float(ctrl[13]);
  float hi = __uint_as_float(ctrl[15]);
  uint stride = gridDim.x * 256;
  for (uint i = blockIdx.x * 256 + threadIdx.x; i < nC; i += stride) {
    uint2 e = cand[i];
    float vf = bf2f((ushort_t)e.x);
    cand[i].x = __float_as_uint(vf);
    if (vf >= lo && vf <= hi) atomicAdd(&h[e.y & (D_SAE - 1)], 1u);
  }
  __syncthreads();
  for (int i = threadIdx.x; i < D_SAE; i += 256) {
    uint c = h[i];
    if (c) atomicAdd(&jcnt[i], c);
  }
}

// ---------------- prefix over column counts -> jcursor + jstart; total -> ctrl[14] ----------------
__global__ __launch_bounds__(256) void prefix_j(const uint* __restrict__ jcnt,
                                                uint* __restrict__ jcursor,
                                                uint* __restrict__ jstart,
                                                uint* __restrict__ ctrl)
{
  __shared__ uint s[256];
  __shared__ uint pref[257];
  int t = threadIdx.x;
  uint sum = 0;
  for (int r = 0; r < 64; ++r) sum += jcnt[t * 64 + r];
  s[t] = sum;
  __syncthreads();
  if (t == 0) {
    uint a = 0;
    for (int i = 0; i < 256; ++i) { pref[i] = a; a += s[i]; }
    pref[256] = a;
    ctrl[14] = a;          // nBand
  }
  __syncthreads();
  uint off = pref[t];
  for (int r = 0; r < 64; ++r) {
    int b = t * 64 + r;
    jcursor[b] = off;
    jstart[b] = off;
    off += jcnt[b];
  }
  if (t == 255) jstart[D_SAE] = pref[256];
}

// ---------------- scatter BAND candidates (list positions) into column-grouped order ----------------
__global__ __launch_bounds__(256) void scatter_j(const uint* __restrict__ ctrl,
                                                 const uint2* __restrict__ cand,
                                                 uint* __restrict__ jcursor,
                                                 uint* __restrict__ candJ)
{
  uint nC = min(ctrl[5], (uint)CAND_CAP);
  uint i = blockIdx.x * 256 + threadIdx.x;
  if (i >= nC) return;
  uint2 e = cand[i];
  float vf = __uint_as_float(e.x);
  if (vf < __uint_as_float(ctrl[13]) || vf > __uint_as_float(ctrl[15])) return;
  uint p = atomicAdd(&jcursor[e.y & (D_SAE - 1)], 1u);
  candJ[p] = i;                                // original list position
}

// ---------------- exact recompute of BAND members: one WAVE per column, W in LDS ----------------
// Per-candidate chain = fmaf(xf[k], w[k], a), k = 0..767 ascending, + benc, relu —
// bitwise-identical to the rounds-1..14 reference chain.
__global__ __launch_bounds__(256) void recompute(
    const float* __restrict__ xf, const float* __restrict__ benc,
    const float* __restrict__ wtf,
    const uint* __restrict__ jstart, const uint* __restrict__ candJ,
    uint2* __restrict__ cand)
{
  __shared__ float wl[4][D_IN];
  const int wv = threadIdx.x >> 6, lane = threadIdx.x & 63;
  const int j = blockIdx.x * 4 + wv;
  uint beg = jstart[j], end = jstart[j + 1];
  const float4* wr4 = (const float4*)(wtf + (size_t)j * D_IN);
  float4* wl4 = (float4*)wl[wv];
#pragma unroll
  for (int k = 0; k < 3; ++k) wl4[lane + 64 * k] = wr4[lane + 64 * k];
  __syncthreads();
  if (beg == end) return;
  float be = benc[j];
  const float* w = wl[wv];
  for (uint s = beg + lane; s < end; s += 64) {
    uint pos = candJ[s];
    uint idx = cand[pos].y;
    uint r = idx >> 14;
    const float* xr = xf + (size_t)r * D_IN;
    float a = 0.f;
#pragma unroll 8
    for (int k = 0; k < D_IN; k += 4) {
      float4 xv = *(const float4*)(xr + k);
      a = fmaf(xv.x, w[k + 0], a);
      a = fmaf(xv.y, w[k + 1], a);
      a = fmaf(xv.z, w[k + 2], a);
      a = fmaf(xv.w, w[k + 3], a);
    }
    float v = fmaxf(a + be, 0.f);
    cand[pos] = make_uint2(__float_as_uint(v), idx);
  }
}

// ---------------- 12-bit hist of bits over the full candidate list ----------------
__global__ __launch_bounds__(256) void hist_exact(const uint* __restrict__ ctrl,
                                                  const uint2* __restrict__ cand,
                                                  uint* __restrict__ histB)
{
  __shared__ uint h[4096];
  for (int i = threadIdx.x; i < 4096; i += 256) h[i] = 0;
  __syncthreads();
  uint nC = min(ctrl[5], (uint)CAND_CAP);
  uint stride = gridDim.x * 256;
  for (uint i = blockIdx.x * 256 + threadIdx.x; i < nC; i += stride)
    atomicAdd(&h[cand[i].x >> 20], 1u);
  __syncthreads();
  for (int i = threadIdx.x; i < 4096; i += 256) {
    uint c = h[i];
    if (c) atomicAdd(&histB[i], c);
  }
}

// ---------------- stage-0 crossing-bin search (ctrl[1], ctrl[2]) ----------------
__global__ __launch_bounds__(256) void select_bin(const uint* __restrict__ hist, uint* ctrl)
{
  __shared__ uint ssum[256];
  int t = threadIdx.x;
  int hi = 4096 - 16 * t;
  uint sum = 0;
  for (int b = hi - 16; b < hi; ++b) sum += hist[b];
  ssum[t] = sum;
  __syncthreads();
  if (t == 0) {
    uint C = 0;
    int tc = 255;
    for (int i = 0; i < 256; ++i) {
      if (C + ssum[i] >= TOTAL_K) { tc = i; break; }
      C += ssum[i];
    }
    int top = 4096 - 16 * tc - 1;
    uint bin = (uint)(top - 15);
    for (int b = top; b >= top - 15; --b) {
      uint c = hist[b];
      if (C + c >= TOTAL_K) { bin = (uint)b; break; }
      C += c;
    }
    ctrl[1] = bin;
    ctrl[2] = C;
  }
}

// ---------------- mid-12-bit hist over candidates inside bin bA ----------------
__global__ __launch_bounds__(256) void hist_mid(const uint* __restrict__ ctrl,
                                                const uint2* __restrict__ cand,
                                                uint* __restrict__ histC)
{
  __shared__ uint h[4096];
  for (int i = threadIdx.x; i < 4096; i += 256) h[i] = 0;
  __syncthreads();
  uint nC = min(ctrl[5], (uint)CAND_CAP);
  uint bA = ctrl[1];
  uint stride = gridDim.x * 256;
  for (uint i = blockIdx.x * 256 + threadIdx.x; i < nC; i += stride) {
    uint b = cand[i].x;
    if ((b >> 20) == bA) atomicAdd(&h[(b >> 8) & 0xFFFu], 1u);
  }
  __syncthreads();
  for (int i = threadIdx.x; i < 4096; i += 256) {
    uint c = h[i];
    if (c) atomicAdd(&histC[i], c);
  }
}

// ---------------- mid crossing-bin search (base C_A -> ctrl[8], ctrl[9]) ----------------
__global__ __launch_bounds__(256) void select_mid(const uint* __restrict__ hist, uint* ctrl)
{
  __shared__ uint ssum[256];
  int t = threadIdx.x;
  int hi = 4096 - 16 * t;
  uint sum = 0;
  for (int b = hi - 16; b < hi; ++b) sum += hist[b];
  ssum[t] = sum;
  __syncthreads();
  if (t == 0) {
    uint C = ctrl[2];
    int tc = 255;
    for (int i = 0; i < 256; ++i) {
      if (C + ssum[i] >= TOTAL_K) { tc = i; break; }
      C += ssum[i];
    }
    int top = 4096 - 16 * tc - 1;
    uint bin = (uint)(top - 15);
    for (int b = top; b >= top - 15; --b) {
      uint c = hist[b];
      if (C + c >= TOTAL_K) { bin = (uint)b; break; }
      C += c;
    }
    ctrl[8] = bin;
    ctrl[9] = C;
  }
}

// ---------------- low-8-bit hist over top24 == target ----------------
__global__ __launch_bounds__(256) void hist_low(const uint* __restrict__ ctrl,
                                                const uint2* __restrict__ cand,
                                                uint* __restrict__ histD)
{
  __shared__ uint h[256];
  h[threadIdx.x] = 0;
  __syncthreads();
  uint nC = min(ctrl[5], (uint)CAND_CAP);
  uint target = (ctrl[1] << 12) | ctrl[8];
  uint stride = gridDim.x * 256;
  for (uint i = blockIdx.x * 256 + threadIdx.x; i < nC; i += stride) {
    uint b = cand[i].x;
    if ((b >> 8) == target) atomicAdd(&h[b & 0xFFu], 1u);
  }
  __syncthreads();
  uint c = h[threadIdx.x];
  if (c) atomicAdd(&histD[threadIdx.x], c);
}

// ---------------- final tau selection (1 tiny block) ----------------
__global__ void select_low(const uint* __restrict__ histD, uint* __restrict__ ctrl)
{
  if (threadIdx.x == 0) {
    uint need = TOTAL_K - ctrl[9];   // >= 1
    uint c = 0, v = 0, cgt = 0;
    for (int b = 255; b >= 0; --b) {
      uint hb = histD[b];
      if (c + hb >= need) { v = (uint)b; cgt = c; break; }
      c += hb;
    }
    uint target = (ctrl[1] << 12) | ctrl[8];
    ctrl[6] = (target << 8) | v;     // tau
    ctrl[7] = need - cgt;            // nt >= 1
  }
}

// ---------------- collect ==tau ties ----------------
__global__ __launch_bounds__(256) void collect_ties(uint* __restrict__ ctrl,
                                                    const uint2* __restrict__ cand,
                                                    uint* __restrict__ tiebuf)
{
  uint nC = min(ctrl[5], (uint)CAND_CAP);
  uint tau = ctrl[6];
  uint stride = gridDim.x * 256;
  for (uint i = blockIdx.x * 256 + threadIdx.x; i < nC; i += stride) {
    if (cand[i].x == tau) {
      uint p = atomicAdd(&ctrl[10], 1u);
      if (p < 2048) tiebuf[p] = cand[i].y;
    }
  }
}

// ---------------- rank ties, keep nt smallest flat indices ----------------
__global__ __launch_bounds__(256) void tie_rank(const uint* __restrict__ ctrl,
                                                const uint* __restrict__ tiebuf,
                                                uint* __restrict__ tiekeep)
{
  __shared__ uint s_tie[2048];
  uint m = min(ctrl[10], 2048u);
  uint nt = ctrl[7];
  for (uint i = threadIdx.x; i < m; i += 256) s_tie[i] = tiebuf[i];
  __syncthreads();
  for (uint i = threadIdx.x; i < m; i += 256) {
    uint my = s_tie[i];
    uint rank = 0;
    for (uint j = 0; j < m; ++j) rank += (s_tie[j] < my) ? 1u : 0u;
    if (rank < nt) tiekeep[rank] = my;
  }
}

// ---------------- count kept entries per row ----------------
__global__ __launch_bounds__(256) void count_rows(const uint* __restrict__ ctrl, const uint2* __restrict__ cand,
                                                  const uint* __restrict__ tiekeep,
                                                  uint* __restrict__ rowcnt)
{
  uint nC = min(ctrl[5], (uint)CAND_CAP);
  uint i = blockIdx.x * 256 + threadIdx.x;
  if (i >= nC) return;
  uint tau = ctrl[6], nt = ctrl[7];
  uint2 e = cand[i];
  bool keep = e.x > tau;
  if (!keep && e.x == tau) {
    for (uint j = 0; j < nt; ++j)
      if (tiekeep[j] == e.y) { keep = true; break; }
  }
  if (keep) atomicAdd(&rowcnt[e.y >> 14], 1u);
}

// ---------------- prefix sum over row counts ----------------
__global__ __launch_bounds__(256) void prefix_rows(const uint* __restrict__ rowcnt,
                                                   uint* __restrict__ rowoff, uint* __restrict__ cursor)
{
  __shared__ uint s[256];
  __shared__ uint pref[257];
  int t = threadIdx.x;
  uint loc[16], sum = 0;
#pragma unroll
  for (int r = 0; r < 16; ++r) { loc[r] = rowcnt[t * 16 + r]; sum += loc[r]; }
  s[t] = sum;
  __syncthreads();
  if (t == 0) {
    uint a = 0;
    for (int i = 0; i < 256; ++i) { pref[i] = a; a += s[i]; }
    pref[256] = a;
  }
  __syncthreads();
  uint off = pref[t];
#pragma unroll
  for (int r = 0; r < 16; ++r) {
    rowoff[t * 16 + r] = off;
    cursor[t * 16 + r] = off;
    off += loc[r];
  }
  if (t == 255) rowoff[BATCH] = off;
}

// ---------------- group kept entries by row ----------------
__global__ __launch_bounds__(256) void group_pass(const uint* __restrict__ ctrl, const uint2* __restrict__ cand,
                                                  const uint* __restrict__ tiekeep,
                                                  uint* __restrict__ cursor, uint2* __restrict__ grouped)
{
  uint nC = min(ctrl[5], (uint)CAND_CAP);
  uint i = blockIdx.x * 256 + threadIdx.x;
  if (i >= nC) return;
  uint tau = ctrl[6], nt = ctrl[7];
  uint2 e = cand[i];
  bool keep = e.x > tau;
  if (!keep && e.x == tau) {
    for (uint j = 0; j < nt; ++j)
      if (tiekeep[j] == e.y) { keep = true; break; }
  }
  if (keep) {
    uint p = atomicAdd(&cursor[e.y >> 14], 1u);
    grouped[p] = make_uint2(e.y, e.x);   // (flat idx, bits)
  }
}

// ---------------- sparse decode (bf16 W_dec, ushort4-vectorized, 192 threads) ----------------
__global__ __launch_bounds__(192) void decode_kernel(const uint* __restrict__ rowoff, const uint2* __restrict__ grouped,
                                                     const ushort_t* __restrict__ wdecb, const float* __restrict__ bdec,
                                                     float* __restrict__ xhat)
{
  int r = blockIdx.x;
  int t = threadIdx.x;          // 0..191, owns cols 4t..4t+3
  uint beg = rowoff[r], end = rowoff[r + 1];
  float4 a = *(const float4*)(bdec + t * 4);
  __shared__ uint2 ch[128];
  for (uint c0 = beg; c0 < end; c0 += 128) {
    uint m = min(128u, end - c0);
    if (t < (int)m) ch[t] = grouped[c0 + t];
    __syncthreads();
    for (uint e = 0; e < m; ++e) {
      uint2 en = ch[e];
      float v = __uint_as_float(en.y);
      uint j = en.x & (D_SAE - 1);
      ushort4 w4 = *(const ushort4*)(wdecb + (size_t)j * D_IN + t * 4);
      a.x = fmaf(v, bf2f(w4.x), a.x);
      a.y = fmaf(v, bf2f(w4.y), a.y);
      a.z = fmaf(v, bf2f(w4.z), a.z);
      a.w = fmaf(v, bf2f(w4.w), a.w);
    }
    __syncthreads();
  }
  *(float4*)(xhat + (size_t)r * D_IN + t * 4) = a;
}

// ---------------- scatter kept values into zeroed z ----------------
__global__ __launch_bounds__(256) void scatter_kept(const uint* __restrict__ ctrl, const uint2* __restrict__ cand,
                                                    const uint* __restrict__ tiekeep,
                                                    float* __restrict__ z)
{
  uint nC = min(ctrl[5], (uint)CAND_CAP);
  uint i = blockIdx.x * 256 + threadIdx.x;
  if (i >= nC) return;
  uint tau = ctrl[6], nt = ctrl[7];
  uint2 e = cand[i];
  bool keep = e.x > tau;
  if (!keep && e.x == tau) {
    for (uint j = 0; j < nt; ++j)
      if (tiekeep[j] == e.y) { keep = true; break; }
  }
  if (keep) z[e.y] = __uint_as_float(e.x);
}

extern "C" void kernel_launch(void* const* d_in, const int* in_sizes, int n_in,
                              void* d_out, int out_size, void* d_ws, size_t ws_size,
                              hipStream_t stream)
{
  const float* x    = (const float*)d_in[0];
  const float* Wenc = (const float*)d_in[1];
  const float* benc = (const float*)d_in[2];
  const float* Wdec = (const float*)d_in[3];
  const float* bdec = (const float*)d_in[4];

  char* outb = (char*)d_out;
  float*    xhat   = (float*)outb;
  ushort_t* xc     = (ushort_t*)outb;
  char*     zb     = outb + (size_t)BATCH * D_IN * 4;
  float*    z      = (float*)zb;
  ushort_t* pre_b  = (ushort_t*)zb;
  float*    wtf    = (float*)(zb + WTF_OFF_Z);
  ushort_t* wtb    = (ushort_t*)(zb + WTB_OFF_Z);
  float*    xf     = (float*)(zb + XF_OFF_Z);
  ushort_t* wdecb  = (ushort_t*)(zb + WDECB_OFF_Z);

  char* ws = (char*)d_ws;
  uint*  ctrl    = (uint*)(ws + CTRL_OFF);
  uint*  histA   = (uint*)(ws + HISTA_OFF);
  uint*  histB   = (uint*)(ws + HISTB_OFF);
  uint*  histC   = (uint*)(ws + HISTC_OFF);
  uint*  histD   = (uint*)(ws + HISTD_OFF);
  uint*  histE   = (uint*)(ws + HISTE_OFF);
  uint*  rowcnt  = (uint*)(ws + ROWCNT_OFF);
  uint*  jcnt    = (uint*)(ws + JCNT_OFF);
  uint*  tiebuf  = (uint*)(ws + TIEBUF_OFF);
  uint*  rowoff  = (uint*)(ws + ROWOFF_OFF);
  uint*  cursor  = (uint*)(ws + CURSOR_OFF);
  uint*  jcursor = (uint*)(ws + JCURSOR_OFF);
  uint*  jstart  = (uint*)(ws + JSTART_OFF);
  uint*  tiekeep = (uint*)(ws + TIEKEEP_OFF);
  uint*  candJ   = (uint*)(ws + CANDJ_OFF);
  uint2* cand    = (uint2*)(ws + CAND_OFF);
  uint2* grouped = (uint2*)(ws + GROUPED_OFF);

  (void)hipMemsetAsync(d_ws, 0, ZERO_BYTES, stream);

  prep_x<<<BATCH * D_IN / 4 / 256, 256, 0, stream>>>(x, bdec, xc, xf);
  transpose_w<<<dim3(D_SAE / 64, D_IN / 64), 256, 0, stream>>>(Wenc, wtf, wtb);
  conv_wdec<<<(D_SAE * D_IN / 4) / 256, 256, 0, stream>>>(Wdec, wdecb);
  mfma_gemm<<<dim3(D_SAE / 128, BATCH / 128), 256, 0, stream>>>(xc, wtb, benc, pre_b, histA);

  select_thr<<<1, 256, 0, stream>>>(histA, ctrl);
  collect_cands<<<1024, 256, 0, stream>>>(pre_b, ctrl, cand);
  fine_list<<<64, 256, 0, stream>>>(ctrl, cand, histE);
  select_fine<<<1, 64, 0, stream>>>(histE, ctrl);

  convert_band<<<64, 256, 0, stream>>>(ctrl, cand, jcnt);
  prefix_j<<<1, 256, 0, stream>>>(jcnt, jcursor, jstart, ctrl);
  scatter_j<<<CAND_CAP / 256, 256, 0, stream>>>(ctrl, cand, jcursor, candJ);
  recompute<<<D_SAE / 4, 256, 0, stream>>>(xf, benc, wtf, jstart, candJ, cand);

  hist_exact<<<128, 256, 0, stream>>>(ctrl, cand, histB);
  select_bin<<<1, 256, 0, stream>>>(histB, ctrl);
  hist_mid<<<128, 256, 0, stream>>>(ctrl, cand, histC);
  select_mid<<<1, 256, 0, stream>>>(histC, ctrl);
  hist_low<<<128, 256, 0, stream>>>(ctrl, cand, histD);
  select_low<<<1, 64, 0, stream>>>(histD, ctrl);
  collect_ties<<<128, 256, 0, stream>>>(ctrl, cand, tiebuf);
  tie_rank<<<1, 256, 0, stream>>>(ctrl, tiebuf, tiekeep);

  // decode BEFORE the z zeroing so wdec_b (in the dead z region) stays intact
  count_rows<<<CAND_CAP / 256, 256, 0, stream>>>(ctrl, cand, tiekeep, rowcnt);
  prefix_rows<<<1, 256, 0, stream>>>(rowcnt, rowoff, cursor);
  group_pass<<<CAND_CAP / 256, 256, 0, stream>>>(ctrl, cand, tiekeep, cursor, grouped);
  decode_kernel<<<BATCH, 192, 0, stream>>>(rowoff, grouped, wdecb, bdec, xhat);

  zero_z<<<2048, 256, 0, stream>>>((uint4*)z);
  scatter_kept<<<CAND_CAP / 256, 256, 0, stream>>>(ctrl, cand, tiekeep, z);
}

// Round 18
// 621.966 us; speedup vs baseline: 1.1634x; 1.0103x over previous
//
#include <hip/hip_runtime.h>

typedef unsigned int uint;
typedef unsigned short ushort_t;
typedef short bf16x8 __attribute__((ext_vector_type(8)));
typedef float f32x4 __attribute__((ext_vector_type(4)));

constexpr int D_IN   = 768;
constexpr int D_SAE  = 16384;   // 2^14
constexpr int BATCH  = 4096;
constexpr int TOTAL_K = 64 * 4096;              // 262144
constexpr size_t NPRE = (size_t)BATCH * D_SAE;  // 67,108,864

// ---------------- workspace layout (bytes) ----------------
// ctrl[1]=bA ctrl[2]=C_A ctrl[3]=thr16_coarse ctrl[5]=nCand ctrl[6]=tau ctrl[7]=nt
// ctrl[8]=bB ctrl[9]=C_B ctrl[10]=tiecnt ctrl[11]=bA_coarse ctrl[12]=C_coarse
// ctrl[13]=band_lo(f32 bits) ctrl[14]=nBand ctrl[15]=band_hi(f32 bits)
constexpr size_t CTRL_OFF    = 0;                          // 16 uints
constexpr size_t HISTA_OFF   = 64;                         // 8192 uints (13-bit approx hist)
constexpr size_t HISTB_OFF   = HISTA_OFF + 8192 * 4;       // 4096 uints (top-12 exact)
constexpr size_t HISTC_OFF   = HISTB_OFF + 4096 * 4;       // 4096 uints (mid-12 exact)
constexpr size_t HISTD_OFF   = HISTC_OFF + 4096 * 4;       // 256 uints (low-8 exact)
constexpr size_t HISTE_OFF   = HISTD_OFF + 256 * 4;        // 8 uints (fine approx sub-bins)
constexpr size_t ROWCNT_OFF  = HISTE_OFF + 64;             // BATCH uints
constexpr size_t JCNT_OFF    = ROWCNT_OFF + BATCH * 4;     // D_SAE uints (64 KB)
constexpr size_t TIEBUF_OFF  = JCNT_OFF + (size_t)D_SAE * 4;  // 2048 uints
constexpr size_t ZERO_BYTES  = TIEBUF_OFF + 2048 * 4;      // memset region end
constexpr size_t ROWOFF_OFF  = ZERO_BYTES;                 // BATCH+1 uints (pad)
constexpr size_t CURSOR_OFF  = ROWOFF_OFF + (BATCH + 64) * 4;
constexpr size_t JCURSOR_OFF = CURSOR_OFF + BATCH * 4;     // D_SAE uints
constexpr size_t JSTART_OFF  = JCURSOR_OFF + (size_t)D_SAE * 4;  // D_SAE+16 uints
constexpr size_t TIEKEEP_OFF = JSTART_OFF + (size_t)(D_SAE + 16) * 4;  // 2048 uints
constexpr int    CAND_CAP    = 1048576;
constexpr size_t CANDJ_OFF   = TIEKEEP_OFF + 2048 * 4;     // uint  * CAND_CAP (4 MB)
constexpr size_t CAND_OFF    = CANDJ_OFF + (size_t)CAND_CAP * 4;  // uint2 * CAND_CAP (8 MB)
constexpr size_t GROUPED_OFF = CAND_OFF + (size_t)CAND_CAP * 8;   // uint2*(TOTAL_K+2048)

// dead-z-region scratch offsets (bytes from z base; z = 268,435,456 B total)
constexpr size_t WTF_OFF_Z   = 134217728;                  // fp32 W^T, 48 MB (after pre_b)
constexpr size_t WTB_OFF_Z   = WTF_OFF_Z + 50331648;       // bf16 W^T, 24 MB
constexpr size_t XF_OFF_Z    = 230686720;                  // fp32 x - b_dec, 12.6 MB
constexpr size_t WDECB_OFF_Z = 243269632;                  // bf16 W_dec, 24 MB (read by decode, pre-memset)

__device__ __forceinline__ ushort_t f2bf(float f) {        // RNE fp32->bf16 (finite inputs)
  uint u = __float_as_uint(f);
  return (ushort_t)((u + 0x7FFFu + ((u >> 16) & 1u)) >> 16);
}
__device__ __forceinline__ float bf2f(ushort_t b) {
  return __uint_as_float(((uint)b) << 16);
}
__device__ __forceinline__ void gload_lds16(const void* g, void* l) {
  auto gp = reinterpret_cast<const __attribute__((address_space(1))) unsigned int*>(
      (unsigned long long)g);
  auto lp = reinterpret_cast<__attribute__((address_space(3))) unsigned int*>(
      (unsigned long long)l);
  __builtin_amdgcn_global_load_lds(gp, lp, 16, 0, 0);
}

// ---------------- zero z with wide contiguous stores ----------------
__global__ __launch_bounds__(256) void zero_z(uint4* __restrict__ z)
{
  const uint4 zero4 = make_uint4(0, 0, 0, 0);
  size_t n16 = NPRE / 4;
  size_t stride = (size_t)gridDim.x * 256;
  for (size_t i = (size_t)blockIdx.x * 256 + threadIdx.x; i < n16; i += stride)
    z[i] = zero4;
}

// ---------------- prep: xc_bf16 = bf16(x - b_dec), xf = fp32(x - b_dec) ----------------
__global__ __launch_bounds__(256) void prep_x(const float* __restrict__ x,
                                              const float* __restrict__ bdec,
                                              ushort_t* __restrict__ xc,
                                              float* __restrict__ xf)
{
  int i = blockIdx.x * 256 + threadIdx.x;     // one float4 per thread
  int k4 = i % (D_IN / 4), r = i / (D_IN / 4);
  float4 v  = *(const float4*)(x + (size_t)r * D_IN + k4 * 4);
  float4 bd = *(const float4*)(bdec + k4 * 4);
  float4 d;
  d.x = v.x - bd.x; d.y = v.y - bd.y; d.z = v.z - bd.z; d.w = v.w - bd.w;
  *(float4*)(xf + (size_t)r * D_IN + k4 * 4) = d;
  ushort4 s;
  s.x = f2bf(d.x); s.y = f2bf(d.y); s.z = f2bf(d.z); s.w = f2bf(d.w);
  *(ushort4*)(xc + (size_t)r * D_IN + k4 * 4) = s;
}

// ---------------- transpose W_enc -> WT_f32 [D_SAE][D_IN] + WT_bf16 ----------------
__global__ __launch_bounds__(256) void transpose_w(const float* __restrict__ W,
                                                   float* __restrict__ wtf,
                                                   ushort_t* __restrict__ wtb)
{
  __shared__ float t[64][65];
  int j0 = blockIdx.x * 64;    // D_SAE block
  int k0 = blockIdx.y * 64;    // D_IN block
  int tx = threadIdx.x & 15, ty = threadIdx.x >> 4;
#pragma unroll
  for (int rr = 0; rr < 4; ++rr) {
    float4 v = *(const float4*)(W + (size_t)(k0 + ty + 16 * rr) * D_SAE + j0 + tx * 4);
    t[tx * 4 + 0][ty + 16 * rr] = v.x;
    t[tx * 4 + 1][ty + 16 * rr] = v.y;
    t[tx * 4 + 2][ty + 16 * rr] = v.z;
    t[tx * 4 + 3][ty + 16 * rr] = v.w;
  }
  __syncthreads();
#pragma unroll
  for (int rr = 0; rr < 4; ++rr) {
    int j = j0 + ty + 16 * rr;
    float4 v;
    v.x = t[ty + 16 * rr][tx * 4 + 0];
    v.y = t[ty + 16 * rr][tx * 4 + 1];
    v.z = t[ty + 16 * rr][tx * 4 + 2];
    v.w = t[ty + 16 * rr][tx * 4 + 3];
    *(float4*)(wtf + (size_t)j * D_IN + k0 + tx * 4) = v;
    ushort4 s;
    s.x = f2bf(v.x); s.y = f2bf(v.y); s.z = f2bf(v.z); s.w = f2bf(v.w);
    *(ushort4*)(wtb + (size_t)j * D_IN + k0 + tx * 4) = s;
  }
}

// ---------------- convert W_dec -> bf16 (row-major [D_SAE][D_IN]) ----------------
__global__ __launch_bounds__(256) void conv_wdec(const float* __restrict__ Wdec,
                                                 ushort_t* __restrict__ wdecb)
{
  size_t i = (size_t)blockIdx.x * 256 + threadIdx.x;   // one float4 per thread
  float4 v = *(const float4*)(Wdec + i * 4);
  ushort4 s;
  s.x = f2bf(v.x); s.y = f2bf(v.y); s.z = f2bf(v.z); s.w = f2bf(v.w);
  *(ushort4*)(wdecb + i * 4) = s;
}

// ---------------- bf16 MFMA GEMM: pre_b = bf16(relu(xc @ WT^T + b_enc)) ----------------
__global__ __launch_bounds__(256, 3) void mfma_gemm(
    const ushort_t* __restrict__ xc, const ushort_t* __restrict__ wtb,
    const float* __restrict__ benc,
    ushort_t* __restrict__ pre_b, uint* __restrict__ histA)
{
  __shared__ char smem[32768];                 // As 16384 | Bs 16384 ; reused as hist[8192]
  ushort_t* As = (ushort_t*)smem;              // [128][64] linear, swizzled granules
  ushort_t* Bs = (ushort_t*)(smem + 16384);
  const int tid = threadIdx.x;
  const int m0 = blockIdx.y * 128;
  const int n0 = blockIdx.x * 128;
  const int lane = tid & 63;
  const int wave = tid >> 6;
  const int wr = wave >> 1, wc = wave & 1;
  const int l15 = lane & 15, l4 = lane >> 4;
  const uint srow = (uint)tid >> 3, sg = (uint)tid & 7;

  f32x4 acc[4][4] = {};

  for (int k0 = 0; k0 < D_IN; k0 += 64) {
#pragma unroll
    for (int is = 0; is < 4; ++is) {
      uint row = srow + is * 32;
      uint gsw = sg ^ (row & 7u);
      gload_lds16(xc + (size_t)(m0 + row) * D_IN + k0 + gsw * 8,
                  As + ((size_t)is * 256 + tid) * 8);
      gload_lds16(wtb + (size_t)(n0 + row) * D_IN + k0 + gsw * 8,
                  Bs + ((size_t)is * 256 + tid) * 8);
    }
    __syncthreads();
#pragma unroll
    for (int ks = 0; ks < 2; ++ks) {
      bf16x8 a[4], b[4];
#pragma unroll
      for (int m = 0; m < 4; ++m) {
        int row = wr * 64 + m * 16 + l15;
        int phys = (ks * 4 + l4) ^ (row & 7);
        a[m] = *(const bf16x8*)(As + row * 64 + phys * 8);
      }
#pragma unroll
      for (int n = 0; n < 4; ++n) {
        int row = wc * 64 + n * 16 + l15;
        int phys = (ks * 4 + l4) ^ (row & 7);
        b[n] = *(const bf16x8*)(Bs + row * 64 + phys * 8);
      }
#pragma unroll
      for (int m = 0; m < 4; ++m)
#pragma unroll
        for (int n = 0; n < 4; ++n)
          acc[m][n] = __builtin_amdgcn_mfma_f32_16x16x32_bf16(a[m], b[n], acc[m][n], 0, 0, 0);
    }
    __syncthreads();
  }

  uint* h = (uint*)smem;
  for (int i = tid; i < 8192; i += 256) h[i] = 0;
  __syncthreads();
#pragma unroll
  for (int m = 0; m < 4; ++m) {
#pragma unroll
    for (int n = 0; n < 4; ++n) {
      int col = n0 + wc * 64 + n * 16 + l15;
      float be = benc[col];
#pragma unroll
      for (int r = 0; r < 4; ++r) {
        int row = m0 + wr * 64 + m * 16 + l4 * 4 + r;
        float v = fmaxf(acc[m][n][r] + be, 0.f);
        ushort_t b16 = f2bf(v);
        pre_b[(size_t)row * D_SAE + col] = b16;
        if (b16) atomicAdd(&h[b16 >> 3], 1u);
      }
    }
  }
  __syncthreads();
  for (int i = tid; i < 8192; i += 256) {
    uint c = h[i];
    if (c) atomicAdd(&histA[i], c);
  }
}

// ---------------- coarse approx crossing bin + conservative collect threshold ----------------
__global__ __launch_bounds__(256) void select_thr(const uint* __restrict__ hist, uint* ctrl)
{
  __shared__ uint ssum[256];
  int t = threadIdx.x;
  int hi = 8192 - 32 * t;
  uint sum = 0;
  for (int b = hi - 32; b < hi; ++b) sum += hist[b];
  ssum[t] = sum;
  __syncthreads();
  if (t == 0) {
    uint C = 0;
    int tc = 255;
    for (int i = 0; i < 256; ++i) {
      if (C + ssum[i] >= TOTAL_K) { tc = i; break; }
      C += ssum[i];
    }
    int top = 8192 - 32 * tc - 1;
    uint bin = (uint)(top - 31);
    for (int b = top; b >= top - 31; --b) {
      uint c = hist[b];
      if (C + c >= TOTAL_K) { bin = (uint)b; break; }
      C += c;
    }
    ctrl[11] = bin;
    ctrl[12] = C;
    float binlo = bf2f((ushort_t)(bin << 3));
    float tcf = binlo - 0.03125f;
    uint thr16;
    if (tcf <= 0.f) thr16 = 1u;
    else thr16 = (__float_as_uint(tcf) + 0xFFFFu) >> 16;
    if (thr16 == 0) thr16 = 1u;
    ctrl[3] = thr16;
  }
}

// ---------------- collect candidates + fused fine (sub-bin) histogram ----------------
// All elements of coarse bin bA pass thr_coarse, so histogramming during collection
// produces exactly the same histE as a separate pass over the candidate list.
__global__ __launch_bounds__(256) void collect_cands(const ushort_t* __restrict__ pre_b,
                                                     uint* __restrict__ ctrl, uint2* __restrict__ cand,
                                                     uint* __restrict__ histE)
{
  __shared__ uint2 ents[2048];
  __shared__ uint scnt, sbase;
  __shared__ uint h8[8];
  if (threadIdx.x == 0) scnt = 0;
  if (threadIdx.x < 8) h8[threadIdx.x] = 0;
  __syncthreads();
  uint thr = ctrl[3];
  uint bA = ctrl[11];
  size_t n8 = NPRE / 8;
  size_t stride = (size_t)gridDim.x * 256;
  for (size_t i = (size_t)blockIdx.x * 256 + threadIdx.x; i < n8; i += stride) {
    uint4 v = ((const uint4*)pre_b)[i];
    uint base = (uint)(i * 8);
    uint vals[8] = {v.x & 0xFFFFu, v.x >> 16, v.y & 0xFFFFu, v.y >> 16,
                    v.z & 0xFFFFu, v.z >> 16, v.w & 0xFFFFu, v.w >> 16};
#pragma unroll
    for (int c = 0; c < 8; ++c) {
      if (vals[c] >= thr) {
        if ((vals[c] >> 3) == bA) atomicAdd(&h8[vals[c] & 7u], 1u);
        uint p = atomicAdd(&scnt, 1u);
        if (p < 2048) ents[p] = make_uint2(vals[c], base + c);
        else { uint q = atomicAdd(&ctrl[5], 1u); if (q < CAND_CAP) cand[q] = make_uint2(vals[c], base + c); }
      }
    }
  }
  __syncthreads();
  uint m = min(scnt, 2048u);
  if (threadIdx.x == 0) sbase = atomicAdd(&ctrl[5], m);
  __syncthreads();
  for (uint i = threadIdx.x; i < m; i += 256) {
    uint p = sbase + i;
    if (p < CAND_CAP) cand[p] = ents[i];
  }
  if (threadIdx.x < 8) {
    uint c = h8[threadIdx.x];
    if (c) atomicAdd(&histE[threadIdx.x], c);
  }
}

// ---------------- exact-bf16 tau_approx -> boundary band [lo, hi] (ctrl[13], ctrl[15]) ----------------
__global__ void select_fine(const uint* __restrict__ histE, uint* __restrict__ ctrl)
{
  if (threadIdx.x == 0) {
    uint C = ctrl[12];
    uint bA = ctrl[11];
    int sb = 0;
    for (int b = 7; b >= 0; --b) {
      uint c = histE[b];
      if (C + c >= TOTAL_K) { sb = b; break; }
      C += c;
      if (b == 0) sb = 0;
    }
    float tf = bf2f((ushort_t)((bA << 3) | (uint)sb));   // tau_approx (bf16-exact)
    // band half-width 0.03125 >= 3x worst-case |exact - bf16approx| (~0.01)
    ctrl[13] = __float_as_uint(tf - 0.03125f);
    ctrl[15] = __float_as_uint(tf + 0.03125f);
  }
}

// ---------------- convert bits16 -> f32 in-place; band -> jcnt; non-band -> histB ----------------
// Non-band values are final (recompute only touches band members), so their top-12
// histogram contribution is complete here; band members are histogrammed in recompute.
__global__ __launch_bounds__(256) void convert_band(const uint* __restrict__ ctrl,
                                                    uint2* __restrict__ cand,
                                                    uint* __restrict__ jcnt,
                                                    uint* __restrict__ histB)
{
  __shared__ uint h32[4096];
  for (int i = threadIdx.x; i < 4096; i += 256) h32[i] = 0;
  __syncthreads();
  uint nC = min(ctrl[5], (uint)CAND_CAP);
  float lo = __uint_as_float(ctrl[13]);
  float hi = __uint_as_float(ctrl[15]);
  uint stride = gridDim.x * 256;
  for (uint i = blockIdx.x * 256 + threadIdx.x; i < nC; i += stride) {
    uint2 e = cand[i];
    float vf = bf2f((ushort_t)e.x);
    uint bits = __float_as_uint(vf);
    cand[i].x = bits;
    if (vf >= lo && vf <= hi) atomicAdd(&jcnt[e.y & (D_SAE - 1)], 1u);
    else atomicAdd(&h32[bits >> 20], 1u);
  }
  __syncthreads();
  for (int i = threadIdx.x; i < 4096; i += 256) {
    uint c = h32[i];
    if (c) atomicAdd(&histB[i], c);
  }
}

// ---------------- prefix over column counts -> jcursor + jstart; total -> ctrl[14] ----------------
__global__ __launch_bounds__(256) void prefix_j(const uint* __restrict__ jcnt,
                                                uint* __restrict__ jcursor,
                                                uint* __restrict__ jstart,
                                                uint* __restrict__ ctrl)
{
  __shared__ uint s[256];
  __shared__ uint pref[257];
  int t = threadIdx.x;
  uint sum = 0;
  for (int r = 0; r < 64; ++r) sum += jcnt[t * 64 + r];
  s[t] = sum;
  __syncthreads();
  if (t == 0) {
    uint a = 0;
    for (int i = 0; i < 256; ++i) { pref[i] = a; a += s[i]; }
    pref[256] = a;
    ctrl[14] = a;          // nBand
  }
  __syncthreads();
  uint off = pref[t];
  for (int r = 0; r < 64; ++r) {
    int b = t * 64 + r;
    jcursor[b] = off;
    jstart[b] = off;
    off += jcnt[b];
  }
  if (t == 255) jstart[D_SAE] = pref[256];
}

// ---------------- scatter BAND candidates (list positions) into column-grouped order ----------------
__global__ __launch_bounds__(256) void scatter_j(const uint* __restrict__ ctrl,
                                                 const uint2* __restrict__ cand,
                                                 uint* __restrict__ jcursor,
                                                 uint* __restrict__ candJ)
{
  uint nC = min(ctrl[5], (uint)CAND_CAP);
  uint i = blockIdx.x * 256 + threadIdx.x;
  if (i >= nC) return;
  uint2 e = cand[i];
  float vf = __uint_as_float(e.x);
  if (vf < __uint_as_float(ctrl[13]) || vf > __uint_as_float(ctrl[15])) return;
  uint p = atomicAdd(&jcursor[e.y & (D_SAE - 1)], 1u);
  candJ[p] = i;                                // original list position
}

// ---------------- exact recompute of BAND members + their histB contribution ----------------
// Per-candidate chain = fmaf(xf[k], w[k], a), k = 0..767 ascending, + benc, relu —
// bitwise-identical to the rounds-1..14 reference chain.
__global__ __launch_bounds__(256) void recompute(
    const float* __restrict__ xf, const float* __restrict__ benc,
    const float* __restrict__ wtf,
    const uint* __restrict__ jstart, const uint* __restrict__ candJ,
    uint2* __restrict__ cand, uint* __restrict__ histB)
{
  __shared__ float wl[4][D_IN];
  __shared__ uint h32[4096];
  const int wv = threadIdx.x >> 6, lane = threadIdx.x & 63;
  const int j = blockIdx.x * 4 + wv;
  for (int i = threadIdx.x; i < 4096; i += 256) h32[i] = 0;
  uint beg = jstart[j], end = jstart[j + 1];
  const float4* wr4 = (const float4*)(wtf + (size_t)j * D_IN);
  float4* wl4 = (float4*)wl[wv];
#pragma unroll
  for (int k = 0; k < 3; ++k) wl4[lane + 64 * k] = wr4[lane + 64 * k];
  __syncthreads();
  if (beg != end) {
    float be = benc[j];
    const float* w = wl[wv];
    for (uint s = beg + lane; s < end; s += 64) {
      uint pos = candJ[s];
      uint idx = cand[pos].y;
      uint r = idx >> 14;
      const float* xr = xf + (size_t)r * D_IN;
      float a = 0.f;
#pragma unroll 8
      for (int k = 0; k < D_IN; k += 4) {
        float4 xv = *(const float4*)(xr + k);
        a = fmaf(xv.x, w[k + 0], a);
        a = fmaf(xv.y, w[k + 1], a);
        a = fmaf(xv.z, w[k + 2], a);
        a = fmaf(xv.w, w[k + 3], a);
      }
      float v = fmaxf(a + be, 0.f);
      uint bits = __float_as_uint(v);
      cand[pos] = make_uint2(bits, idx);
      atomicAdd(&h32[bits >> 20], 1u);
    }
  }
  __syncthreads();
  for (int i = threadIdx.x; i < 4096; i += 256) {
    uint c = h32[i];
    if (c) atomicAdd(&histB[i], c);
  }
}

// ---------------- stage-0 crossing-bin search (ctrl[1], ctrl[2]) ----------------
__global__ __launch_bounds__(256) void select_bin(const uint* __restrict__ hist, uint* ctrl)
{
  __shared__ uint ssum[256];
  int t = threadIdx.x;
  int hi = 4096 - 16 * t;
  uint sum = 0;
  for (int b = hi - 16; b < hi; ++b) sum += hist[b];
  ssum[t] = sum;
  __syncthreads();
  if (t == 0) {
    uint C = 0;
    int tc = 255;
    for (int i = 0; i < 256; ++i) {
      if (C + ssum[i] >= TOTAL_K) { tc = i; break; }
      C += ssum[i];
    }
    int top = 4096 - 16 * tc - 1;
    uint bin = (uint)(top - 15);
    for (int b = top; b >= top - 15; --b) {
      uint c = hist[b];
      if (C + c >= TOTAL_K) { bin = (uint)b; break; }
      C += c;
    }
    ctrl[1] = bin;
    ctrl[2] = C;
  }
}

// ---------------- mid-12-bit hist over candidates inside bin bA ----------------
__global__ __launch_bounds__(256) void hist_mid(const uint* __restrict__ ctrl,
                                                const uint2* __restrict__ cand,
                                                uint* __restrict__ histC)
{
  __shared__ uint h[4096];
  for (int i = threadIdx.x; i < 4096; i += 256) h[i] = 0;
  __syncthreads();
  uint nC = min(ctrl[5], (uint)CAND_CAP);
  uint bA = ctrl[1];
  uint stride = gridDim.x * 256;
  for (uint i = blockIdx.x * 256 + threadIdx.x; i < nC; i += stride) {
    uint b = cand[i].x;
    if ((b >> 20) == bA) atomicAdd(&h[(b >> 8) & 0xFFFu], 1u);
  }
  __syncthreads();
  for (int i = threadIdx.x; i < 4096; i += 256) {
    uint c = h[i];
    if (c) atomicAdd(&histC[i], c);
  }
}

// ---------------- mid crossing-bin search (base C_A -> ctrl[8], ctrl[9]) ----------------
__global__ __launch_bounds__(256) void select_mid(const uint* __restrict__ hist, uint* ctrl)
{
  __shared__ uint ssum[256];
  int t = threadIdx.x;
  int hi = 4096 - 16 * t;
  uint sum = 0;
  for (int b = hi - 16; b < hi; ++b) sum += hist[b];
  ssum[t] = sum;
  __syncthreads();
  if (t == 0) {
    uint C = ctrl[2];
    int tc = 255;
    for (int i = 0; i < 256; ++i) {
      if (C + ssum[i] >= TOTAL_K) { tc = i; break; }
      C += ssum[i];
    }
    int top = 4096 - 16 * tc - 1;
    uint bin = (uint)(top - 15);
    for (int b = top; b >= top - 15; --b) {
      uint c = hist[b];
      if (C + c >= TOTAL_K) { bin = (uint)b; break; }
      C += c;
    }
    ctrl[8] = bin;
    ctrl[9] = C;
  }
}

// ---------------- low-8-bit hist over top24 == target ----------------
__global__ __launch_bounds__(256) void hist_low(const uint* __restrict__ ctrl,
                                                const uint2* __restrict__ cand,
                                                uint* __restrict__ histD)
{
  __shared__ uint h[256];
  h[threadIdx.x] = 0;
  __syncthreads();
  uint nC = min(ctrl[5], (uint)CAND_CAP);
  uint target = (ctrl[1] << 12) | ctrl[8];
  uint stride = gridDim.x * 256;
  for (uint i = blockIdx.x * 256 + threadIdx.x; i < nC; i += stride) {
    uint b = cand[i].x;
    if ((b >> 8) == target) atomicAdd(&h[b & 0xFFu], 1u);
  }
  __syncthreads();
  uint c = h[threadIdx.x];
  if (c) atomicAdd(&histD[threadIdx.x], c);
}

// ---------------- final tau selection (1 tiny block) ----------------
__global__ void select_low(const uint* __restrict__ histD, uint* __restrict__ ctrl)
{
  if (threadIdx.x == 0) {
    uint need = TOTAL_K - ctrl[9];   // >= 1
    uint c = 0, v = 0, cgt = 0;
    for (int b = 255; b >= 0; --b) {
      uint hb = histD[b];
      if (c + hb >= need) { v = (uint)b; cgt = c; break; }
      c += hb;
    }
    uint target = (ctrl[1] << 12) | ctrl[8];
    ctrl[6] = (target << 8) | v;     // tau
    ctrl[7] = need - cgt;            // nt >= 1
  }
}

// ---------------- collect ==tau ties + rowcnt for clear keeps (>tau) ----------------
__global__ __launch_bounds__(256) void collect_ties(uint* __restrict__ ctrl,
                                                    const uint2* __restrict__ cand,
                                                    uint* __restrict__ tiebuf,
                                                    uint* __restrict__ rowcnt)
{
  uint nC = min(ctrl[5], (uint)CAND_CAP);
  uint tau = ctrl[6];
  uint stride = gridDim.x * 256;
  for (uint i = blockIdx.x * 256 + threadIdx.x; i < nC; i += stride) {
    uint2 e = cand[i];
    if (e.x > tau) {
      atomicAdd(&rowcnt[e.y >> 14], 1u);
    } else if (e.x == tau) {
      uint p = atomicAdd(&ctrl[10], 1u);
      if (p < 2048) tiebuf[p] = e.y;
    }
  }
}

// ---------------- rank ties, keep nt smallest flat indices (+ their rowcnt) ----------------
__global__ __launch_bounds__(256) void tie_rank(const uint* __restrict__ ctrl,
                                                const uint* __restrict__ tiebuf,
                                                uint* __restrict__ tiekeep,
                                                uint* __restrict__ rowcnt)
{
  __shared__ uint s_tie[2048];
  uint m = min(ctrl[10], 2048u);
  uint nt = ctrl[7];
  for (uint i = threadIdx.x; i < m; i += 256) s_tie[i] = tiebuf[i];
  __syncthreads();
  for (uint i = threadIdx.x; i < m; i += 256) {
    uint my = s_tie[i];
    uint rank = 0;
    for (uint j = 0; j < m; ++j) rank += (s_tie[j] < my) ? 1u : 0u;
    if (rank < nt) {
      tiekeep[rank] = my;
      atomicAdd(&rowcnt[my >> 14], 1u);
    }
  }
}

// ---------------- prefix sum over row counts ----------------
__global__ __launch_bounds__(256) void prefix_rows(const uint* __restrict__ rowcnt,
                                                   uint* __restrict__ rowoff, uint* __restrict__ cursor)
{
  __shared__ uint s[256];
  __shared__ uint pref[257];
  int t = threadIdx.x;
  uint loc[16], sum = 0;
#pragma unroll
  for (int r = 0; r < 16; ++r) { loc[r] = rowcnt[t * 16 + r]; sum += loc[r]; }
  s[t] = sum;
  __syncthreads();
  if (t == 0) {
    uint a = 0;
    for (int i = 0; i < 256; ++i) { pref[i] = a; a += s[i]; }
    pref[256] = a;
  }
  __syncthreads();
  uint off = pref[t];
#pragma unroll
  for (int r = 0; r < 16; ++r) {
    rowoff[t * 16 + r] = off;
    cursor[t * 16 + r] = off;
    off += loc[r];
  }
  if (t == 255) rowoff[BATCH] = off;
}

// ---------------- group kept entries by row ----------------
__global__ __launch_bounds__(256) void group_pass(const uint* __restrict__ ctrl, const uint2* __restrict__ cand,
                                                  const uint* __restrict__ tiekeep,
                                                  uint* __restrict__ cursor, uint2* __restrict__ grouped)
{
  uint nC = min(ctrl[5], (uint)CAND_CAP);
  uint i = blockIdx.x * 256 + threadIdx.x;
  if (i >= nC) return;
  uint tau = ctrl[6], nt = ctrl[7];
  uint2 e = cand[i];
  bool keep = e.x > tau;
  if (!keep && e.x == tau) {
    for (uint j = 0; j < nt; ++j)
      if (tiekeep[j] == e.y) { keep = true; break; }
  }
  if (keep) {
    uint p = atomicAdd(&cursor[e.y >> 14], 1u);
    grouped[p] = make_uint2(e.y, e.x);   // (flat idx, bits)
  }
}

// ---------------- sparse decode (bf16 W_dec, ushort4-vectorized, 192 threads) ----------------
__global__ __launch_bounds__(192) void decode_kernel(const uint* __restrict__ rowoff, const uint2* __restrict__ grouped,
                                                     const ushort_t* __restrict__ wdecb, const float* __restrict__ bdec,
                                                     float* __restrict__ xhat)
{
  int r = blockIdx.x;
  int t = threadIdx.x;          // 0..191, owns cols 4t..4t+3
  uint beg = rowoff[r], end = rowoff[r + 1];
  float4 a = *(const float4*)(bdec + t * 4);
  __shared__ uint2 ch[128];
  for (uint c0 = beg; c0 < end; c0 += 128) {
    uint m = min(128u, end - c0);
    if (t < (int)m) ch[t] = grouped[c0 + t];
    __syncthreads();
    for (uint e = 0; e < m; ++e) {
      uint2 en = ch[e];
      float v = __uint_as_float(en.y);
      uint j = en.x & (D_SAE - 1);
      ushort4 w4 = *(const ushort4*)(wdecb + (size_t)j * D_IN + t * 4);
      a.x = fmaf(v, bf2f(w4.x), a.x);
      a.y = fmaf(v, bf2f(w4.y), a.y);
      a.z = fmaf(v, bf2f(w4.z), a.z);
      a.w = fmaf(v, bf2f(w4.w), a.w);
    }
    __syncthreads();
  }
  *(float4*)(xhat + (size_t)r * D_IN + t * 4) = a;
}

// ---------------- scatter kept values into zeroed z ----------------
__global__ __launch_bounds__(256) void scatter_kept(const uint* __restrict__ ctrl, const uint2* __restrict__ cand,
                                                    const uint* __restrict__ tiekeep,
                                                    float* __restrict__ z)
{
  uint nC = min(ctrl[5], (uint)CAND_CAP);
  uint i = blockIdx.x * 256 + threadIdx.x;
  if (i >= nC) return;
  uint tau = ctrl[6], nt = ctrl[7];
  uint2 e = cand[i];
  bool keep = e.x > tau;
  if (!keep && e.x == tau) {
    for (uint j = 0; j < nt; ++j)
      if (tiekeep[j] == e.y) { keep = true; break; }
  }
  if (keep) z[e.y] = __uint_as_float(e.x);
}

extern "C" void kernel_launch(void* const* d_in, const int* in_sizes, int n_in,
                              void* d_out, int out_size, void* d_ws, size_t ws_size,
                              hipStream_t stream)
{
  const float* x    = (const float*)d_in[0];
  const float* Wenc = (const float*)d_in[1];
  const float* benc = (const float*)d_in[2];
  const float* Wdec = (const float*)d_in[3];
  const float* bdec = (const float*)d_in[4];

  char* outb = (char*)d_out;
  float*    xhat   = (float*)outb;
  ushort_t* xc     = (ushort_t*)outb;
  char*     zb     = outb + (size_t)BATCH * D_IN * 4;
  float*    z      = (float*)zb;
  ushort_t* pre_b  = (ushort_t*)zb;
  float*    wtf    = (float*)(zb + WTF_OFF_Z);
  ushort_t* wtb    = (ushort_t*)(zb + WTB_OFF_Z);
  float*    xf     = (float*)(zb + XF_OFF_Z);
  ushort_t* wdecb  = (ushort_t*)(zb + WDECB_OFF_Z);

  char* ws = (char*)d_ws;
  uint*  ctrl    = (uint*)(ws + CTRL_OFF);
  uint*  histA   = (uint*)(ws + HISTA_OFF);
  uint*  histB   = (uint*)(ws + HISTB_OFF);
  uint*  histC   = (uint*)(ws + HISTC_OFF);
  uint*  histD   = (uint*)(ws + HISTD_OFF);
  uint*  histE   = (uint*)(ws + HISTE_OFF);
  uint*  rowcnt  = (uint*)(ws + ROWCNT_OFF);
  uint*  jcnt    = (uint*)(ws + JCNT_OFF);
  uint*  tiebuf  = (uint*)(ws + TIEBUF_OFF);
  uint*  rowoff  = (uint*)(ws + ROWOFF_OFF);
  uint*  cursor  = (uint*)(ws + CURSOR_OFF);
  uint*  jcursor = (uint*)(ws + JCURSOR_OFF);
  uint*  jstart  = (uint*)(ws + JSTART_OFF);
  uint*  tiekeep = (uint*)(ws + TIEKEEP_OFF);
  uint*  candJ   = (uint*)(ws + CANDJ_OFF);
  uint2* cand    = (uint2*)(ws + CAND_OFF);
  uint2* grouped = (uint2*)(ws + GROUPED_OFF);

  (void)hipMemsetAsync(d_ws, 0, ZERO_BYTES, stream);

  prep_x<<<BATCH * D_IN / 4 / 256, 256, 0, stream>>>(x, bdec, xc, xf);
  transpose_w<<<dim3(D_SAE / 64, D_IN / 64), 256, 0, stream>>>(Wenc, wtf, wtb);
  conv_wdec<<<(D_SAE * D_IN / 4) / 256, 256, 0, stream>>>(Wdec, wdecb);
  mfma_gemm<<<dim3(D_SAE / 128, BATCH / 128), 256, 0, stream>>>(xc, wtb, benc, pre_b, histA);

  select_thr<<<1, 256, 0, stream>>>(histA, ctrl);
  collect_cands<<<1024, 256, 0, stream>>>(pre_b, ctrl, cand, histE);
  select_fine<<<1, 64, 0, stream>>>(histE, ctrl);

  convert_band<<<64, 256, 0, stream>>>(ctrl, cand, jcnt, histB);
  prefix_j<<<1, 256, 0, stream>>>(jcnt, jcursor, jstart, ctrl);
  scatter_j<<<CAND_CAP / 256, 256, 0, stream>>>(ctrl, cand, jcursor, candJ);
  recompute<<<D_SAE / 4, 256, 0, stream>>>(xf, benc, wtf, jstart, candJ, cand, histB);

  select_bin<<<1, 256, 0, stream>>>(histB, ctrl);
  hist_mid<<<128, 256, 0, stream>>>(ctrl, cand, histC);
  select_mid<<<1, 256, 0, stream>>>(histC, ctrl);
  hist_low<<<128, 256, 0, stream>>>(ctrl, cand, histD);
  select_low<<<1, 64, 0, stream>>>(histD, ctrl);
  collect_ties<<<128, 256, 0, stream>>>(ctrl, cand, tiebuf, rowcnt);
  tie_rank<<<1, 256, 0, stream>>>(ctrl, tiebuf, tiekeep, rowcnt);

  // decode BEFORE the z zeroing so wdec_b (in the dead z region) stays intact
  prefix_rows<<<1, 256, 0, stream>>>(rowcnt, rowoff, cursor);
  group_pass<<<CAND_CAP / 256, 256, 0, stream>>>(ctrl, cand, tiekeep, cursor, grouped);
  decode_kernel<<<BATCH, 192, 0, stream>>>(rowoff, grouped, wdecb, bdec, xhat);

  zero_z<<<2048, 256, 0, stream>>>((uint4*)z);
  scatter_kept<<<CAND_CAP / 256, 256, 0, stream>>>(ctrl, cand, tiekeep, z);
}